// Round 1
// baseline (444.854 us; speedup 1.0000x reference)
//
#include <hip/hip_runtime.h>
#include <hip/hip_bf16.h>
#include <math.h>

#define N_NODES 100000
#define N_EDGES 1600000
#define IN_CH 256
#define HID_CH 32
#define OUT_CH 8
#define N_GRAPHS 64

// ---------------- workspace layout (in floats) ----------------
// deg   : N_NODES
// dinv  : N_NODES
// y1    : N_NODES*32
// acc1  : N_NODES*32
// y2    : N_NODES*8
// acc2  : N_NODES*8
// psum  : 64*8
// pcnt  : 64
#define OFF_DEG   0
#define OFF_DINV  (OFF_DEG + N_NODES)
#define OFF_Y1    (OFF_DINV + N_NODES)
#define OFF_ACC1  (OFF_Y1 + N_NODES*HID_CH)
#define OFF_Y2    (OFF_ACC1 + N_NODES*HID_CH)
#define OFF_ACC2  (OFF_Y2 + N_NODES*OUT_CH)
#define OFF_PSUM  (OFF_ACC2 + N_NODES*OUT_CH)
#define OFF_PCNT  (OFF_PSUM + N_GRAPHS*OUT_CH)

__global__ void deg_kernel(const int* __restrict__ dst, float* __restrict__ deg) {
    int e = blockIdx.x * blockDim.x + threadIdx.x;
    if (e < N_EDGES) {
        atomicAdd(&deg[dst[e]], 1.0f);
    }
}

__global__ void dinv_kernel(const float* __restrict__ deg, float* __restrict__ dinv) {
    int n = blockIdx.x * blockDim.x + threadIdx.x;
    if (n < N_NODES) {
        // +1 for the self-loop; deg >= 1 always so no zero-guard needed
        dinv[n] = rsqrtf(deg[n] + 1.0f);
    }
}

// xw = x @ W1 ; y1 = xw * dinv[n]; acc1 init = y1 (self-loop term)
// 8 nodes per 256-thread block: 32 lanes per node, lane%32 = out channel.
__global__ __launch_bounds__(256) void gemm1_kernel(
        const float* __restrict__ x, const float* __restrict__ W1,
        const float* __restrict__ dinv,
        float* __restrict__ y1, float* __restrict__ acc1) {
    __shared__ float w[IN_CH * HID_CH];     // 32 KB
    __shared__ float xr[8][IN_CH];          // 8 KB
    const int t = threadIdx.x;

    // load W1 (8192 floats) via float4: 2048 float4 / 256 threads = 8 each
    const float4* W4 = (const float4*)W1;
    float4* w4 = (float4*)w;
#pragma unroll
    for (int i = 0; i < 8; i++) w4[t + i * 256] = W4[t + i * 256];

    const int node0 = blockIdx.x * 8;       // 12500 blocks * 8 = 100000 exactly
    // load 8 x-rows (2048 floats) via float4: 512 float4 / 256 threads = 2 each
    const float4* x4 = (const float4*)(x + (size_t)node0 * IN_CH);
    float4* xr4 = (float4*)xr;
#pragma unroll
    for (int i = 0; i < 2; i++) xr4[t + i * 256] = x4[t + i * 256];
    __syncthreads();

    const int local = t >> 5;   // node within block
    const int c = t & 31;       // output channel
    const int node = node0 + local;
    const float* xrow = xr[local];
    float acc = 0.0f;
#pragma unroll 8
    for (int k = 0; k < IN_CH; k++) {
        acc = fmaf(xrow[k], w[k * HID_CH + c], acc);
    }
    const float v = acc * dinv[node];
    y1[(size_t)node * HID_CH + c] = v;
    acc1[(size_t)node * HID_CH + c] = v;
}

// scatter: acc[dst][c] += y[src][c], C lanes per edge, grid-stride
template <int C, int LOGC>
__global__ void scatter_kernel(const int* __restrict__ src, const int* __restrict__ dst,
                               const float* __restrict__ y, float* __restrict__ acc) {
    const long long total = (long long)N_EDGES * C;
    long long idx = (long long)blockIdx.x * blockDim.x + threadIdx.x;
    const long long stride = (long long)gridDim.x * blockDim.x;
    for (; idx < total; idx += stride) {
        const int e = (int)(idx >> LOGC);
        const int c = (int)(idx & (C - 1));
        const int s = src[e];
        const int d = dst[e];
        atomicAdd(&acc[(size_t)d * C + c], y[(size_t)s * C + c]);
    }
}

// h = relu(acc1*dinv + b1); y2 = (h @ W2) * dinv; acc2 init = y2
__global__ __launch_bounds__(256) void layer2_kernel(
        const float* __restrict__ acc1, const float* __restrict__ dinv,
        const float* __restrict__ b1, const float* __restrict__ W2,
        float* __restrict__ y2, float* __restrict__ acc2) {
    __shared__ float w2s[HID_CH * OUT_CH];  // 256 floats
    __shared__ float b1s[HID_CH];
    const int t = threadIdx.x;
    if (t < HID_CH * OUT_CH) w2s[t] = W2[t];
    if (t < HID_CH) b1s[t] = b1[t];
    __syncthreads();

    const int n = blockIdx.x * blockDim.x + t;
    if (n >= N_NODES) return;
    const float dv = dinv[n];

    float h[HID_CH];
    const float4* a4 = (const float4*)(acc1 + (size_t)n * HID_CH);
#pragma unroll
    for (int i = 0; i < 8; i++) {
        float4 v = a4[i];
        h[i * 4 + 0] = fmaxf(v.x * dv + b1s[i * 4 + 0], 0.0f);
        h[i * 4 + 1] = fmaxf(v.y * dv + b1s[i * 4 + 1], 0.0f);
        h[i * 4 + 2] = fmaxf(v.z * dv + b1s[i * 4 + 2], 0.0f);
        h[i * 4 + 3] = fmaxf(v.w * dv + b1s[i * 4 + 3], 0.0f);
    }
    float o[OUT_CH] = {0, 0, 0, 0, 0, 0, 0, 0};
#pragma unroll
    for (int k = 0; k < HID_CH; k++) {
        const float hk = h[k];
#pragma unroll
        for (int c = 0; c < OUT_CH; c++) o[c] = fmaf(hk, w2s[k * OUT_CH + c], o[c]);
    }
#pragma unroll
    for (int c = 0; c < OUT_CH; c++) {
        const float v = o[c] * dv;
        y2[(size_t)n * OUT_CH + c] = v;
        acc2[(size_t)n * OUT_CH + c] = v;
    }
}

// o = relu(acc2*dinv + b2); per-graph partial sums via LDS, then global atomics
__global__ __launch_bounds__(256) void pool_kernel(
        const float* __restrict__ acc2, const float* __restrict__ dinv,
        const float* __restrict__ b2, const int* __restrict__ batch,
        float* __restrict__ psum, float* __restrict__ pcnt) {
    __shared__ float ls[N_GRAPHS * OUT_CH];  // 512
    __shared__ float lc[N_GRAPHS];
    __shared__ float b2s[OUT_CH];
    const int t = threadIdx.x;
    ls[t] = 0.0f; ls[t + 256] = 0.0f;
    if (t < N_GRAPHS) lc[t] = 0.0f;
    if (t < OUT_CH) b2s[t] = b2[t];
    __syncthreads();

    const int n = blockIdx.x * blockDim.x + t;
    if (n < N_NODES) {
        const int g = batch[n];
        const float dv = dinv[n];
#pragma unroll
        for (int c = 0; c < OUT_CH; c++) {
            const float o = fmaxf(acc2[(size_t)n * OUT_CH + c] * dv + b2s[c], 0.0f);
            atomicAdd(&ls[g * OUT_CH + c], o);
        }
        atomicAdd(&lc[g], 1.0f);
    }
    __syncthreads();
    if (t < N_GRAPHS * OUT_CH) {
        const int g = t >> 3;
        if (lc[g] > 0.0f) atomicAdd(&psum[t], ls[t]);
    }
    if (t < N_GRAPHS && lc[t] > 0.0f) atomicAdd(&pcnt[t], lc[t]);
}

__global__ void logsoftmax_kernel(const float* __restrict__ psum,
                                  const float* __restrict__ pcnt,
                                  float* __restrict__ out) {
    const int g = threadIdx.x;
    if (g >= N_GRAPHS) return;
    const float cnt = fmaxf(pcnt[g], 1.0f);
    float p[OUT_CH];
    float m = -INFINITY;
#pragma unroll
    for (int c = 0; c < OUT_CH; c++) {
        p[c] = psum[g * OUT_CH + c] / cnt;
        m = fmaxf(m, p[c]);
    }
    float s = 0.0f;
#pragma unroll
    for (int c = 0; c < OUT_CH; c++) s += expf(p[c] - m);
    const float lse = logf(s);
#pragma unroll
    for (int c = 0; c < OUT_CH; c++) out[g * OUT_CH + c] = p[c] - m - lse;
}

extern "C" void kernel_launch(void* const* d_in, const int* in_sizes, int n_in,
                              void* d_out, int out_size, void* d_ws, size_t ws_size,
                              hipStream_t stream) {
    const float* x    = (const float*)d_in[0];
    const int* eidx   = (const int*)d_in[1];   // [2, E] int32 (JAX x64 disabled)
    const int* batch  = (const int*)d_in[2];
    const float* W1   = (const float*)d_in[3];
    const float* b1   = (const float*)d_in[4];
    const float* W2   = (const float*)d_in[5];
    const float* b2   = (const float*)d_in[6];
    float* out = (float*)d_out;

    const int* src = eidx;
    const int* dst = eidx + N_EDGES;

    float* ws   = (float*)d_ws;
    float* deg  = ws + OFF_DEG;
    float* dinv = ws + OFF_DINV;
    float* y1   = ws + OFF_Y1;
    float* acc1 = ws + OFF_ACC1;
    float* y2   = ws + OFF_Y2;
    float* acc2 = ws + OFF_ACC2;
    float* psum = ws + OFF_PSUM;
    float* pcnt = ws + OFF_PCNT;

    // zero degree counters and pooling accumulators
    hipMemsetAsync(deg, 0, N_NODES * sizeof(float), stream);
    hipMemsetAsync(psum, 0, (N_GRAPHS * OUT_CH + N_GRAPHS) * sizeof(float), stream);

    deg_kernel<<<(N_EDGES + 255) / 256, 256, 0, stream>>>(dst, deg);
    dinv_kernel<<<(N_NODES + 255) / 256, 256, 0, stream>>>(deg, dinv);
    gemm1_kernel<<<N_NODES / 8, 256, 0, stream>>>(x, W1, dinv, y1, acc1);
    scatter_kernel<HID_CH, 5><<<2048, 256, 0, stream>>>(src, dst, y1, acc1);
    layer2_kernel<<<(N_NODES + 255) / 256, 256, 0, stream>>>(acc1, dinv, b1, W2, y2, acc2);
    scatter_kernel<OUT_CH, 3><<<1024, 256, 0, stream>>>(src, dst, y2, acc2);
    pool_kernel<<<(N_NODES + 255) / 256, 256, 0, stream>>>(acc2, dinv, b2, batch, psum, pcnt);
    logsoftmax_kernel<<<1, 64, 0, stream>>>(psum, pcnt, out);
}

// Round 2
// 388.746 us; speedup vs baseline: 1.1443x; 1.1443x over previous
//
#include <hip/hip_runtime.h>
#include <hip/hip_bf16.h>
#include <math.h>

#define N_NODES 100000
#define N_EDGES 1600000
#define IN_CH 256
#define HID_CH 32
#define OUT_CH 8
#define N_GRAPHS 64

#define SCAN_TILE 1024
#define NBLK_SCAN ((N_NODES + SCAN_TILE - 1) / SCAN_TILE)   // 98

// ---------------- workspace layout (in 4-byte words) ----------------
#define OFF_DEG   0                              // uint[N]
#define OFF_DINV  (OFF_DEG + N_NODES)            // float[N]
#define OFF_CUR   (OFF_DINV + N_NODES)           // uint[N]  (scan result -> fill cursor -> row end)
#define OFF_BSUM  (OFF_CUR + N_NODES)            // uint[128]
#define OFF_CSR   (OFF_BSUM + 128)               // int[E]   (src ids grouped by dst)
#define OFF_Y1    (OFF_CSR + N_EDGES)            // float[N*32]
#define OFF_AGG1  (OFF_Y1 + N_NODES*HID_CH)      // float[N*32]
#define OFF_Y2    (OFF_AGG1 + N_NODES*HID_CH)    // float[N*8]
#define OFF_AGG2  (OFF_Y2 + N_NODES*OUT_CH)      // float[N*8]
#define OFF_PSUM  (OFF_AGG2 + N_NODES*OUT_CH)    // float[64*8]
#define OFF_PCNT  (OFF_PSUM + N_GRAPHS*OUT_CH)   // float[64]

__global__ void deg_kernel(const int* __restrict__ dst, unsigned* __restrict__ deg) {
    int e = blockIdx.x * blockDim.x + threadIdx.x;
    if (e < N_EDGES) atomicAdd(&deg[dst[e]], 1u);
}

__global__ void dinv_kernel(const unsigned* __restrict__ deg, float* __restrict__ dinv) {
    int n = blockIdx.x * blockDim.x + threadIdx.x;
    if (n < N_NODES) dinv[n] = rsqrtf((float)deg[n] + 1.0f);  // +1 = self-loop
}

// block-level exclusive scan: 256 threads x 4 elems = 1024/block
__global__ __launch_bounds__(256) void scan1_kernel(const unsigned* __restrict__ deg,
                                                    unsigned* __restrict__ cur,
                                                    unsigned* __restrict__ bsum) {
    __shared__ unsigned s[256];
    const int t = threadIdx.x;
    const int base = blockIdx.x * SCAN_TILE + t * 4;
    unsigned v[4];
#pragma unroll
    for (int i = 0; i < 4; i++) v[i] = (base + i < N_NODES) ? deg[base + i] : 0u;
    const unsigned tsum = v[0] + v[1] + v[2] + v[3];
    s[t] = tsum;
    __syncthreads();
    for (int off = 1; off < 256; off <<= 1) {
        unsigned x = (t >= off) ? s[t - off] : 0u;
        __syncthreads();
        s[t] += x;
        __syncthreads();
    }
    unsigned ex = s[t] - tsum;  // exclusive prefix of this thread's chunk
#pragma unroll
    for (int i = 0; i < 4; i++) {
        if (base + i < N_NODES) cur[base + i] = ex;
        ex += v[i];
    }
    if (t == 255) bsum[blockIdx.x] = s[255];
}

__global__ void scan2_kernel(unsigned* __restrict__ bsum) {
    if (threadIdx.x == 0) {
        unsigned run = 0;
        for (int i = 0; i < NBLK_SCAN; i++) {
            unsigned v = bsum[i];
            bsum[i] = run;
            run += v;
        }
    }
}

__global__ void scan3_kernel(unsigned* __restrict__ cur, const unsigned* __restrict__ bsum) {
    int n = blockIdx.x * blockDim.x + threadIdx.x;
    if (n < N_NODES) cur[n] += bsum[n >> 10];
}

// CSR fill: csr[pos] = src, grouped by dst. After this, cur[n] = row end.
__global__ void fill_kernel(const int* __restrict__ src, const int* __restrict__ dst,
                            unsigned* __restrict__ cur, int* __restrict__ csr) {
    int e = blockIdx.x * blockDim.x + threadIdx.x;
    if (e < N_EDGES) {
        unsigned pos = atomicAdd(&cur[dst[e]], 1u);
        csr[pos] = src[e];
    }
}

// y1 = (x @ W1) * dinv[n]; 8 nodes / 256-thread block, 32 lanes per node
__global__ __launch_bounds__(256) void gemm1_kernel(
        const float* __restrict__ x, const float* __restrict__ W1,
        const float* __restrict__ dinv, float* __restrict__ y1) {
    __shared__ float w[IN_CH * HID_CH];     // 32 KB
    __shared__ float xr[8][IN_CH];          // 8 KB
    const int t = threadIdx.x;

    const float4* W4 = (const float4*)W1;
    float4* w4 = (float4*)w;
#pragma unroll
    for (int i = 0; i < 8; i++) w4[t + i * 256] = W4[t + i * 256];

    const int node0 = blockIdx.x * 8;
    const float4* x4 = (const float4*)(x + (size_t)node0 * IN_CH);
    float4* xr4 = (float4*)xr;
#pragma unroll
    for (int i = 0; i < 2; i++) xr4[t + i * 256] = x4[t + i * 256];
    __syncthreads();

    const int local = t >> 5;
    const int c = t & 31;
    const int node = node0 + local;
    const float* xrow = xr[local];
    float acc = 0.0f;
#pragma unroll 8
    for (int k = 0; k < IN_CH; k++) acc = fmaf(xrow[k], w[k * HID_CH + c], acc);
    y1[(size_t)node * HID_CH + c] = acc * dinv[node];
}

// agg1[n] = y1[n] + sum_{s in N(n)} y1[s] ; 32 lanes per node
__global__ __launch_bounds__(256) void gather32_kernel(
        const unsigned* __restrict__ cur, const unsigned* __restrict__ deg,
        const int* __restrict__ csr, const float* __restrict__ y,
        float* __restrict__ agg) {
    const int t = threadIdx.x;
    const int node = blockIdx.x * 8 + (t >> 5);
    if (node >= N_NODES) return;
    const int lane = t & 31;
    const unsigned cnt = deg[node];
    const unsigned base = cur[node] - cnt;   // cur = row end after fill
    float acc = y[(size_t)node * HID_CH + lane];  // self-loop
    unsigned j = 0;
    for (; j + 2 <= cnt; j += 2) {
        const int s0 = csr[base + j];
        const int s1 = csr[base + j + 1];
        const float a0 = y[(size_t)s0 * HID_CH + lane];
        const float a1 = y[(size_t)s1 * HID_CH + lane];
        acc += a0;
        acc += a1;
    }
    if (j < cnt) {
        const int s0 = csr[base + j];
        acc += y[(size_t)s0 * HID_CH + lane];
    }
    agg[(size_t)node * HID_CH + lane] = acc;
}

// agg2[n] = y2[n] + sum y2[s] ; 8 lanes per node
__global__ __launch_bounds__(256) void gather8_kernel(
        const unsigned* __restrict__ cur, const unsigned* __restrict__ deg,
        const int* __restrict__ csr, const float* __restrict__ y,
        float* __restrict__ agg) {
    const int t = threadIdx.x;
    const int node = blockIdx.x * 32 + (t >> 3);
    if (node >= N_NODES) return;
    const int lane = t & 7;
    const unsigned cnt = deg[node];
    const unsigned base = cur[node] - cnt;
    float acc = y[(size_t)node * OUT_CH + lane];
    unsigned j = 0;
    for (; j + 2 <= cnt; j += 2) {
        const int s0 = csr[base + j];
        const int s1 = csr[base + j + 1];
        const float a0 = y[(size_t)s0 * OUT_CH + lane];
        const float a1 = y[(size_t)s1 * OUT_CH + lane];
        acc += a0;
        acc += a1;
    }
    if (j < cnt) {
        const int s0 = csr[base + j];
        acc += y[(size_t)s0 * OUT_CH + lane];
    }
    agg[(size_t)node * OUT_CH + lane] = acc;
}

// h = relu(agg1*dinv + b1); y2 = (h @ W2) * dinv
__global__ __launch_bounds__(256) void layer2_kernel(
        const float* __restrict__ agg1, const float* __restrict__ dinv,
        const float* __restrict__ b1, const float* __restrict__ W2,
        float* __restrict__ y2) {
    __shared__ float w2s[HID_CH * OUT_CH];
    __shared__ float b1s[HID_CH];
    const int t = threadIdx.x;
    if (t < HID_CH * OUT_CH) w2s[t] = W2[t];
    if (t < HID_CH) b1s[t] = b1[t];
    __syncthreads();

    const int n = blockIdx.x * blockDim.x + t;
    if (n >= N_NODES) return;
    const float dv = dinv[n];

    float h[HID_CH];
    const float4* a4 = (const float4*)(agg1 + (size_t)n * HID_CH);
#pragma unroll
    for (int i = 0; i < 8; i++) {
        float4 v = a4[i];
        h[i * 4 + 0] = fmaxf(v.x * dv + b1s[i * 4 + 0], 0.0f);
        h[i * 4 + 1] = fmaxf(v.y * dv + b1s[i * 4 + 1], 0.0f);
        h[i * 4 + 2] = fmaxf(v.z * dv + b1s[i * 4 + 2], 0.0f);
        h[i * 4 + 3] = fmaxf(v.w * dv + b1s[i * 4 + 3], 0.0f);
    }
    float o[OUT_CH] = {0, 0, 0, 0, 0, 0, 0, 0};
#pragma unroll
    for (int k = 0; k < HID_CH; k++) {
        const float hk = h[k];
#pragma unroll
        for (int c = 0; c < OUT_CH; c++) o[c] = fmaf(hk, w2s[k * OUT_CH + c], o[c]);
    }
#pragma unroll
    for (int c = 0; c < OUT_CH; c++)
        y2[(size_t)n * OUT_CH + c] = o[c] * dv;
}

// o = relu(agg2*dinv + b2); per-graph partial sums via LDS, then global atomics
__global__ __launch_bounds__(256) void pool_kernel(
        const float* __restrict__ agg2, const float* __restrict__ dinv,
        const float* __restrict__ b2, const int* __restrict__ batch,
        float* __restrict__ psum, float* __restrict__ pcnt) {
    __shared__ float ls[N_GRAPHS * OUT_CH];
    __shared__ float lc[N_GRAPHS];
    __shared__ float b2s[OUT_CH];
    const int t = threadIdx.x;
    ls[t] = 0.0f; ls[t + 256] = 0.0f;
    if (t < N_GRAPHS) lc[t] = 0.0f;
    if (t < OUT_CH) b2s[t] = b2[t];
    __syncthreads();

    const int n = blockIdx.x * blockDim.x + t;
    if (n < N_NODES) {
        const int g = batch[n];
        const float dv = dinv[n];
#pragma unroll
        for (int c = 0; c < OUT_CH; c++) {
            const float o = fmaxf(agg2[(size_t)n * OUT_CH + c] * dv + b2s[c], 0.0f);
            atomicAdd(&ls[g * OUT_CH + c], o);
        }
        atomicAdd(&lc[g], 1.0f);
    }
    __syncthreads();
    if (t < N_GRAPHS * OUT_CH) {
        const int g = t >> 3;
        if (lc[g] > 0.0f) atomicAdd(&psum[t], ls[t]);
    }
    if (t < N_GRAPHS && lc[t] > 0.0f) atomicAdd(&pcnt[t], lc[t]);
}

__global__ void logsoftmax_kernel(const float* __restrict__ psum,
                                  const float* __restrict__ pcnt,
                                  float* __restrict__ out) {
    const int g = threadIdx.x;
    if (g >= N_GRAPHS) return;
    const float cnt = fmaxf(pcnt[g], 1.0f);
    float p[OUT_CH];
    float m = -INFINITY;
#pragma unroll
    for (int c = 0; c < OUT_CH; c++) {
        p[c] = psum[g * OUT_CH + c] / cnt;
        m = fmaxf(m, p[c]);
    }
    float s = 0.0f;
#pragma unroll
    for (int c = 0; c < OUT_CH; c++) s += expf(p[c] - m);
    const float lse = logf(s);
#pragma unroll
    for (int c = 0; c < OUT_CH; c++) out[g * OUT_CH + c] = p[c] - m - lse;
}

extern "C" void kernel_launch(void* const* d_in, const int* in_sizes, int n_in,
                              void* d_out, int out_size, void* d_ws, size_t ws_size,
                              hipStream_t stream) {
    const float* x    = (const float*)d_in[0];
    const int* eidx   = (const int*)d_in[1];   // [2, E] int32 (JAX x64 disabled)
    const int* batch  = (const int*)d_in[2];
    const float* W1   = (const float*)d_in[3];
    const float* b1   = (const float*)d_in[4];
    const float* W2   = (const float*)d_in[5];
    const float* b2   = (const float*)d_in[6];
    float* out = (float*)d_out;

    const int* src = eidx;
    const int* dst = eidx + N_EDGES;

    char* wsb = (char*)d_ws;
    unsigned* deg  = (unsigned*)(wsb) + OFF_DEG;
    float*    dinv = (float*)(wsb) + OFF_DINV;
    unsigned* cur  = (unsigned*)(wsb) + OFF_CUR;
    unsigned* bsum = (unsigned*)(wsb) + OFF_BSUM;
    int*      csr  = (int*)(wsb) + OFF_CSR;
    float*    y1   = (float*)(wsb) + OFF_Y1;
    float*    agg1 = (float*)(wsb) + OFF_AGG1;
    float*    y2   = (float*)(wsb) + OFF_Y2;
    float*    agg2 = (float*)(wsb) + OFF_AGG2;
    float*    psum = (float*)(wsb) + OFF_PSUM;
    float*    pcnt = (float*)(wsb) + OFF_PCNT;

    hipMemsetAsync(deg, 0, N_NODES * sizeof(unsigned), stream);
    hipMemsetAsync(psum, 0, (N_GRAPHS * OUT_CH + N_GRAPHS) * sizeof(float), stream);

    deg_kernel<<<(N_EDGES + 255) / 256, 256, 0, stream>>>(dst, deg);
    dinv_kernel<<<(N_NODES + 255) / 256, 256, 0, stream>>>(deg, dinv);
    scan1_kernel<<<NBLK_SCAN, 256, 0, stream>>>(deg, cur, bsum);
    scan2_kernel<<<1, 64, 0, stream>>>(bsum);
    scan3_kernel<<<(N_NODES + 255) / 256, 256, 0, stream>>>(cur, bsum);
    fill_kernel<<<(N_EDGES + 255) / 256, 256, 0, stream>>>(src, dst, cur, csr);
    gemm1_kernel<<<N_NODES / 8, 256, 0, stream>>>(x, W1, dinv, y1);
    gather32_kernel<<<(N_NODES + 7) / 8, 256, 0, stream>>>(cur, deg, csr, y1, agg1);
    layer2_kernel<<<(N_NODES + 255) / 256, 256, 0, stream>>>(agg1, dinv, b1, W2, y2);
    gather8_kernel<<<(N_NODES + 31) / 32, 256, 0, stream>>>(cur, deg, csr, y2, agg2);
    pool_kernel<<<(N_NODES + 255) / 256, 256, 0, stream>>>(agg2, dinv, b2, batch, psum, pcnt);
    logsoftmax_kernel<<<1, 64, 0, stream>>>(psum, pcnt, out);
}

// Round 3
// 238.777 us; speedup vs baseline: 1.8631x; 1.6281x over previous
//
#include <hip/hip_runtime.h>
#include <hip/hip_bf16.h>
#include <math.h>

#define N_NODES 100000
#define N_EDGES 1600000
#define IN_CH 256
#define HID_CH 32
#define OUT_CH 8
#define N_GRAPHS 64

// bucket sort params
#define BUCK_SHIFT 9
#define NODES_PER_BUCK 512
#define NBUCK ((N_NODES + NODES_PER_BUCK - 1) / NODES_PER_BUCK)   // 196
#define CAP 10240                     // slots per bucket (mean 8163 + 23 sigma)
#define CHUNK 8192                    // edges per p1 block
#define NBLK_P1 ((N_EDGES + CHUNK - 1) / CHUNK)                   // 196

// ---------------- workspace layout (in 4-byte words) ----------------
#define OFF_DEG    0                                // uint[N]
#define OFF_DINV   (OFF_DEG + N_NODES)              // float[N]
#define OFF_ROWS   (OFF_DINV + N_NODES)             // uint[N] row start
#define OFF_CNTG   (OFF_ROWS + N_NODES)             // uint[NBUCK]
#define OFF_BSTART (OFF_CNTG + NBUCK)               // uint[NBUCK]
#define OFF_CSR    (OFF_BSTART + NBUCK)             // int[E]
#define OFF_Y1     (OFF_CSR + N_EDGES)              // float[N*32]
#define OFF_AGG1   (OFF_Y1 + N_NODES*HID_CH)        // float[N*32]  (bbuf aliases here)
#define OFF_Y2     (OFF_AGG1 + N_NODES*HID_CH)      // float[N*8]
#define OFF_AGG2   (OFF_Y2 + N_NODES*OUT_CH)        // float[N*8]
#define OFF_PSUM   (OFF_AGG2 + N_NODES*OUT_CH)      // float[64*8]
#define OFF_PCNT   (OFF_PSUM + N_GRAPHS*OUT_CH)     // float[64]

// pass 1: partition edges into per-bucket arenas, packed (src | dlow<<17)
__global__ __launch_bounds__(256) void p1_partition(
        const int* __restrict__ src, const int* __restrict__ dst,
        unsigned* __restrict__ cntg, unsigned* __restrict__ bbuf) {
    __shared__ unsigned hcnt[NBUCK];
    __shared__ unsigned hcur[NBUCK];
    const int t = threadIdx.x;
    const long long e0 = (long long)blockIdx.x * CHUNK;

    for (int i = t; i < NBUCK; i += 256) hcnt[i] = 0;
    __syncthreads();
#pragma unroll
    for (int i = 0; i < CHUNK / 256; i++) {
        const long long e = e0 + t + i * 256;
        if (e < N_EDGES) atomicAdd(&hcnt[((unsigned)dst[e]) >> BUCK_SHIFT], 1u);
    }
    __syncthreads();
    for (int i = t; i < NBUCK; i += 256) {
        const unsigned c = hcnt[i];
        const unsigned r = c ? atomicAdd(&cntg[i], c) : 0u;
        hcur[i] = (unsigned)i * CAP + r;    // absolute running cursor in arena
    }
    __syncthreads();
#pragma unroll
    for (int i = 0; i < CHUNK / 256; i++) {
        const long long e = e0 + t + i * 256;
        if (e < N_EDGES) {
            const unsigned d = (unsigned)dst[e];
            const unsigned b = d >> BUCK_SHIFT;
            const unsigned pos = atomicAdd(&hcur[b], 1u);
            if (pos - b * CAP < CAP)  // overflow guard (never expected)
                bbuf[pos] = (unsigned)src[e] | ((d & (NODES_PER_BUCK - 1)) << 17);
        }
    }
}

// tiny exclusive scan over bucket counts
__global__ void scanb_kernel(const unsigned* __restrict__ cntg,
                             unsigned* __restrict__ bstart) {
    if (threadIdx.x == 0) {
        unsigned run = 0;
        for (int i = 0; i < NBUCK; i++) {
            unsigned c = cntg[i]; if (c > CAP) c = CAP;
            bstart[i] = run;
            run += c;
        }
    }
}

// pass 2: per bucket, build node-grouped CSR in LDS, flush coalesced;
// emit deg, rowstart, dinv per node.
__global__ __launch_bounds__(256) void p2_build(
        const unsigned* __restrict__ cntg, const unsigned* __restrict__ bstart,
        const unsigned* __restrict__ bbuf, int* __restrict__ csr,
        unsigned* __restrict__ deg, unsigned* __restrict__ rowstart,
        float* __restrict__ dinv) {
    __shared__ unsigned hist[NODES_PER_BUCK];
    __shared__ unsigned start[NODES_PER_BUCK];
    __shared__ unsigned cur[NODES_PER_BUCK];
    __shared__ unsigned s[256];
    __shared__ int lcsr[CAP];
    const int b = blockIdx.x;
    const int t = threadIdx.x;
    unsigned cnt = cntg[b]; if (cnt > CAP) cnt = CAP;
    const unsigned gbase = bstart[b];
    const unsigned* mybuf = bbuf + (size_t)b * CAP;

    hist[t] = 0; hist[t + 256] = 0;
    __syncthreads();
    for (unsigned i = t; i < cnt; i += 256) atomicAdd(&hist[mybuf[i] >> 17], 1u);
    __syncthreads();
    // exclusive scan of hist[512]
    const unsigned v0 = hist[2 * t], v1 = hist[2 * t + 1];
    const unsigned tsum = v0 + v1;
    s[t] = tsum;
    __syncthreads();
    for (int off = 1; off < 256; off <<= 1) {
        unsigned x = (t >= off) ? s[t - off] : 0u;
        __syncthreads();
        s[t] += x;
        __syncthreads();
    }
    const unsigned ex = s[t] - tsum;
    start[2 * t] = ex;       cur[2 * t] = ex;
    start[2 * t + 1] = ex + v0; cur[2 * t + 1] = ex + v0;
    __syncthreads();
    for (unsigned i = t; i < cnt; i += 256) {
        const unsigned p = mybuf[i];
        const unsigned pos = atomicAdd(&cur[p >> 17], 1u);
        lcsr[pos] = (int)(p & 0x1FFFFu);
    }
    __syncthreads();
    for (unsigned i = t; i < cnt; i += 256) csr[gbase + i] = lcsr[i];
    // node outputs (hist still holds per-node degree)
    const int n0 = b * NODES_PER_BUCK;
#pragma unroll
    for (int i = t; i < NODES_PER_BUCK; i += 256) {
        const int n = n0 + i;
        if (n < N_NODES) {
            const unsigned d = hist[i];
            deg[n] = d;
            rowstart[n] = gbase + start[i];
            dinv[n] = rsqrtf((float)d + 1.0f);   // +1 = self-loop
        }
    }
}

// y1 = (x @ W1) * dinv[n]; 8 nodes / 256-thread block, 32 lanes per node
__global__ __launch_bounds__(256) void gemm1_kernel(
        const float* __restrict__ x, const float* __restrict__ W1,
        const float* __restrict__ dinv, float* __restrict__ y1) {
    __shared__ float w[IN_CH * HID_CH];     // 32 KB
    __shared__ float xr[8][IN_CH];          // 8 KB
    const int t = threadIdx.x;

    const float4* W4 = (const float4*)W1;
    float4* w4 = (float4*)w;
#pragma unroll
    for (int i = 0; i < 8; i++) w4[t + i * 256] = W4[t + i * 256];

    const int node0 = blockIdx.x * 8;
    const float4* x4 = (const float4*)(x + (size_t)node0 * IN_CH);
    float4* xr4 = (float4*)xr;
#pragma unroll
    for (int i = 0; i < 2; i++) xr4[t + i * 256] = x4[t + i * 256];
    __syncthreads();

    const int local = t >> 5;
    const int c = t & 31;
    const int node = node0 + local;
    const float* xrow = xr[local];
    float acc = 0.0f;
#pragma unroll 8
    for (int k = 0; k < IN_CH; k++) acc = fmaf(xrow[k], w[k * HID_CH + c], acc);
    y1[(size_t)node * HID_CH + c] = acc * dinv[node];
}

// agg1[n] = y1[n] + sum_{s in N(n)} y1[s] ; 32 lanes per node
__global__ __launch_bounds__(256) void gather32_kernel(
        const unsigned* __restrict__ rowstart, const unsigned* __restrict__ deg,
        const int* __restrict__ csr, const float* __restrict__ y,
        float* __restrict__ agg) {
    const int t = threadIdx.x;
    const int node = blockIdx.x * 8 + (t >> 5);
    if (node >= N_NODES) return;
    const int lane = t & 31;
    const unsigned cnt = deg[node];
    const unsigned base = rowstart[node];
    float acc = y[(size_t)node * HID_CH + lane];  // self-loop
    unsigned j = 0;
    for (; j + 2 <= cnt; j += 2) {
        const int s0 = csr[base + j];
        const int s1 = csr[base + j + 1];
        const float a0 = y[(size_t)s0 * HID_CH + lane];
        const float a1 = y[(size_t)s1 * HID_CH + lane];
        acc += a0;
        acc += a1;
    }
    if (j < cnt) acc += y[(size_t)csr[base + j] * HID_CH + lane];
    agg[(size_t)node * HID_CH + lane] = acc;
}

// agg2[n] = y2[n] + sum y2[s] ; 8 lanes per node
__global__ __launch_bounds__(256) void gather8_kernel(
        const unsigned* __restrict__ rowstart, const unsigned* __restrict__ deg,
        const int* __restrict__ csr, const float* __restrict__ y,
        float* __restrict__ agg) {
    const int t = threadIdx.x;
    const int node = blockIdx.x * 32 + (t >> 3);
    if (node >= N_NODES) return;
    const int lane = t & 7;
    const unsigned cnt = deg[node];
    const unsigned base = rowstart[node];
    float acc = y[(size_t)node * OUT_CH + lane];
    unsigned j = 0;
    for (; j + 2 <= cnt; j += 2) {
        const int s0 = csr[base + j];
        const int s1 = csr[base + j + 1];
        const float a0 = y[(size_t)s0 * OUT_CH + lane];
        const float a1 = y[(size_t)s1 * OUT_CH + lane];
        acc += a0;
        acc += a1;
    }
    if (j < cnt) acc += y[(size_t)csr[base + j] * OUT_CH + lane];
    agg[(size_t)node * OUT_CH + lane] = acc;
}

// h = relu(agg1*dinv + b1); y2 = (h @ W2) * dinv
__global__ __launch_bounds__(256) void layer2_kernel(
        const float* __restrict__ agg1, const float* __restrict__ dinv,
        const float* __restrict__ b1, const float* __restrict__ W2,
        float* __restrict__ y2) {
    __shared__ float w2s[HID_CH * OUT_CH];
    __shared__ float b1s[HID_CH];
    const int t = threadIdx.x;
    if (t < HID_CH * OUT_CH) w2s[t] = W2[t];
    if (t < HID_CH) b1s[t] = b1[t];
    __syncthreads();

    const int n = blockIdx.x * blockDim.x + t;
    if (n >= N_NODES) return;
    const float dv = dinv[n];

    float h[HID_CH];
    const float4* a4 = (const float4*)(agg1 + (size_t)n * HID_CH);
#pragma unroll
    for (int i = 0; i < 8; i++) {
        float4 v = a4[i];
        h[i * 4 + 0] = fmaxf(v.x * dv + b1s[i * 4 + 0], 0.0f);
        h[i * 4 + 1] = fmaxf(v.y * dv + b1s[i * 4 + 1], 0.0f);
        h[i * 4 + 2] = fmaxf(v.z * dv + b1s[i * 4 + 2], 0.0f);
        h[i * 4 + 3] = fmaxf(v.w * dv + b1s[i * 4 + 3], 0.0f);
    }
    float o[OUT_CH] = {0, 0, 0, 0, 0, 0, 0, 0};
#pragma unroll
    for (int k = 0; k < HID_CH; k++) {
        const float hk = h[k];
#pragma unroll
        for (int c = 0; c < OUT_CH; c++) o[c] = fmaf(hk, w2s[k * OUT_CH + c], o[c]);
    }
#pragma unroll
    for (int c = 0; c < OUT_CH; c++)
        y2[(size_t)n * OUT_CH + c] = o[c] * dv;
}

// o = relu(agg2*dinv + b2); per-graph partial sums via LDS, then global atomics
__global__ __launch_bounds__(256) void pool_kernel(
        const float* __restrict__ agg2, const float* __restrict__ dinv,
        const float* __restrict__ b2, const int* __restrict__ batch,
        float* __restrict__ psum, float* __restrict__ pcnt) {
    __shared__ float ls[N_GRAPHS * OUT_CH];
    __shared__ float lc[N_GRAPHS];
    __shared__ float b2s[OUT_CH];
    const int t = threadIdx.x;
    ls[t] = 0.0f; ls[t + 256] = 0.0f;
    if (t < N_GRAPHS) lc[t] = 0.0f;
    if (t < OUT_CH) b2s[t] = b2[t];
    __syncthreads();

    const int n = blockIdx.x * blockDim.x + t;
    if (n < N_NODES) {
        const int g = batch[n];
        const float dv = dinv[n];
#pragma unroll
        for (int c = 0; c < OUT_CH; c++) {
            const float o = fmaxf(agg2[(size_t)n * OUT_CH + c] * dv + b2s[c], 0.0f);
            atomicAdd(&ls[g * OUT_CH + c], o);
        }
        atomicAdd(&lc[g], 1.0f);
    }
    __syncthreads();
    if (t < N_GRAPHS * OUT_CH) {
        const int g = t >> 3;
        if (lc[g] > 0.0f) atomicAdd(&psum[t], ls[t]);
    }
    if (t < N_GRAPHS && lc[t] > 0.0f) atomicAdd(&pcnt[t], lc[t]);
}

__global__ void logsoftmax_kernel(const float* __restrict__ psum,
                                  const float* __restrict__ pcnt,
                                  float* __restrict__ out) {
    const int g = threadIdx.x;
    if (g >= N_GRAPHS) return;
    const float cnt = fmaxf(pcnt[g], 1.0f);
    float p[OUT_CH];
    float m = -INFINITY;
#pragma unroll
    for (int c = 0; c < OUT_CH; c++) {
        p[c] = psum[g * OUT_CH + c] / cnt;
        m = fmaxf(m, p[c]);
    }
    float s = 0.0f;
#pragma unroll
    for (int c = 0; c < OUT_CH; c++) s += expf(p[c] - m);
    const float lse = logf(s);
#pragma unroll
    for (int c = 0; c < OUT_CH; c++) out[g * OUT_CH + c] = p[c] - m - lse;
}

extern "C" void kernel_launch(void* const* d_in, const int* in_sizes, int n_in,
                              void* d_out, int out_size, void* d_ws, size_t ws_size,
                              hipStream_t stream) {
    const float* x    = (const float*)d_in[0];
    const int* eidx   = (const int*)d_in[1];   // [2, E] int32 (JAX x64 disabled)
    const int* batch  = (const int*)d_in[2];
    const float* W1   = (const float*)d_in[3];
    const float* b1   = (const float*)d_in[4];
    const float* W2   = (const float*)d_in[5];
    const float* b2   = (const float*)d_in[6];
    float* out = (float*)d_out;

    const int* src = eidx;
    const int* dst = eidx + N_EDGES;

    char* wsb = (char*)d_ws;
    unsigned* deg   = (unsigned*)(wsb) + OFF_DEG;
    float*    dinv  = (float*)(wsb) + OFF_DINV;
    unsigned* rows  = (unsigned*)(wsb) + OFF_ROWS;
    unsigned* cntg  = (unsigned*)(wsb) + OFF_CNTG;
    unsigned* bst   = (unsigned*)(wsb) + OFF_BSTART;
    int*      csr   = (int*)(wsb) + OFF_CSR;
    float*    y1    = (float*)(wsb) + OFF_Y1;
    float*    agg1  = (float*)(wsb) + OFF_AGG1;
    float*    y2    = (float*)(wsb) + OFF_Y2;
    float*    agg2  = (float*)(wsb) + OFF_AGG2;
    float*    psum  = (float*)(wsb) + OFF_PSUM;
    float*    pcnt  = (float*)(wsb) + OFF_PCNT;
    unsigned* bbuf  = (unsigned*)agg1;          // arena aliases agg1 (freed before gather32)

    hipMemsetAsync(cntg, 0, NBUCK * sizeof(unsigned), stream);
    hipMemsetAsync(psum, 0, (N_GRAPHS * OUT_CH + N_GRAPHS) * sizeof(float), stream);

    p1_partition<<<NBLK_P1, 256, 0, stream>>>(src, dst, cntg, bbuf);
    scanb_kernel<<<1, 64, 0, stream>>>(cntg, bst);
    p2_build<<<NBUCK, 256, 0, stream>>>(cntg, bst, bbuf, csr, deg, rows, dinv);
    gemm1_kernel<<<N_NODES / 8, 256, 0, stream>>>(x, W1, dinv, y1);
    gather32_kernel<<<(N_NODES + 7) / 8, 256, 0, stream>>>(rows, deg, csr, y1, agg1);
    layer2_kernel<<<(N_NODES + 255) / 256, 256, 0, stream>>>(agg1, dinv, b1, W2, y2);
    gather8_kernel<<<(N_NODES + 31) / 32, 256, 0, stream>>>(rows, deg, csr, y2, agg2);
    pool_kernel<<<(N_NODES + 255) / 256, 256, 0, stream>>>(agg2, dinv, b2, batch, psum, pcnt);
    logsoftmax_kernel<<<1, 64, 0, stream>>>(psum, pcnt, out);
}

// Round 4
// 185.301 us; speedup vs baseline: 2.4007x; 1.2886x over previous
//
#include <hip/hip_runtime.h>
#include <hip/hip_bf16.h>
#include <math.h>

#define N_NODES 100000
#define N_EDGES 1600000
#define IN_CH 256
#define HID_CH 32
#define OUT_CH 8
#define N_GRAPHS 64

// bucket sort params
#define BUCK_SHIFT 9
#define NODES_PER_BUCK 512
#define NBUCK ((N_NODES + NODES_PER_BUCK - 1) / NODES_PER_BUCK)   // 196
#define CAP 10240
#define CHUNK 8192
#define NBLK_P1 ((N_EDGES + CHUNK - 1) / CHUNK)                   // 196

// ---------------- workspace layout (in 4-byte words) ----------------
#define OFF_DEG    0                                // uint[N]
#define OFF_DINV   (OFF_DEG + N_NODES)              // float[N]
#define OFF_ROWS   (OFF_DINV + N_NODES)             // uint[N] row start
#define OFF_CNTG   (OFF_ROWS + N_NODES)             // uint[NBUCK]
#define OFF_BSTART (OFF_CNTG + NBUCK)               // uint[NBUCK]
#define OFF_CSR    (OFF_BSTART + NBUCK)             // int[E]
#define OFF_Y1     (OFF_CSR + N_EDGES)              // float[N*32]
#define OFF_AGG1   (OFF_Y1 + N_NODES*HID_CH)        // float[N*32]  (bbuf aliases here)
#define OFF_Y2     (OFF_AGG1 + N_NODES*HID_CH)      // float[N*8]
#define OFF_AGG2   (OFF_Y2 + N_NODES*OUT_CH)        // float[N*8]
#define OFF_PSUM   (OFF_AGG2 + N_NODES*OUT_CH)      // float[64*8]
#define OFF_PCNT   (OFF_PSUM + N_GRAPHS*OUT_CH)     // float[64]

// pass 1: partition edges into per-bucket arenas, packed (src | dlow<<17)
__global__ __launch_bounds__(256) void p1_partition(
        const int* __restrict__ src, const int* __restrict__ dst,
        unsigned* __restrict__ cntg, unsigned* __restrict__ bbuf) {
    __shared__ unsigned hcnt[NBUCK];
    __shared__ unsigned hcur[NBUCK];
    const int t = threadIdx.x;
    const long long e0 = (long long)blockIdx.x * CHUNK;

    for (int i = t; i < NBUCK; i += 256) hcnt[i] = 0;
    __syncthreads();
#pragma unroll
    for (int i = 0; i < CHUNK / 256; i++) {
        const long long e = e0 + t + i * 256;
        if (e < N_EDGES) atomicAdd(&hcnt[((unsigned)dst[e]) >> BUCK_SHIFT], 1u);
    }
    __syncthreads();
    for (int i = t; i < NBUCK; i += 256) {
        const unsigned c = hcnt[i];
        const unsigned r = c ? atomicAdd(&cntg[i], c) : 0u;
        hcur[i] = (unsigned)i * CAP + r;
    }
    __syncthreads();
#pragma unroll
    for (int i = 0; i < CHUNK / 256; i++) {
        const long long e = e0 + t + i * 256;
        if (e < N_EDGES) {
            const unsigned d = (unsigned)dst[e];
            const unsigned b = d >> BUCK_SHIFT;
            const unsigned pos = atomicAdd(&hcur[b], 1u);
            if (pos - b * CAP < CAP)
                bbuf[pos] = (unsigned)src[e] | ((d & (NODES_PER_BUCK - 1)) << 17);
        }
    }
}

__global__ void scanb_kernel(const unsigned* __restrict__ cntg,
                             unsigned* __restrict__ bstart) {
    if (threadIdx.x == 0) {
        unsigned run = 0;
        for (int i = 0; i < NBUCK; i++) {
            unsigned c = cntg[i]; if (c > CAP) c = CAP;
            bstart[i] = run;
            run += c;
        }
    }
}

// pass 2: per bucket, build node-grouped CSR in LDS, flush coalesced
__global__ __launch_bounds__(256) void p2_build(
        const unsigned* __restrict__ cntg, const unsigned* __restrict__ bstart,
        const unsigned* __restrict__ bbuf, int* __restrict__ csr,
        unsigned* __restrict__ deg, unsigned* __restrict__ rowstart,
        float* __restrict__ dinv) {
    __shared__ unsigned hist[NODES_PER_BUCK];
    __shared__ unsigned start[NODES_PER_BUCK];
    __shared__ unsigned cur[NODES_PER_BUCK];
    __shared__ unsigned s[256];
    __shared__ int lcsr[CAP];
    const int b = blockIdx.x;
    const int t = threadIdx.x;
    unsigned cnt = cntg[b]; if (cnt > CAP) cnt = CAP;
    const unsigned gbase = bstart[b];
    const unsigned* mybuf = bbuf + (size_t)b * CAP;

    hist[t] = 0; hist[t + 256] = 0;
    __syncthreads();
    for (unsigned i = t; i < cnt; i += 256) atomicAdd(&hist[mybuf[i] >> 17], 1u);
    __syncthreads();
    const unsigned v0 = hist[2 * t], v1 = hist[2 * t + 1];
    const unsigned tsum = v0 + v1;
    s[t] = tsum;
    __syncthreads();
    for (int off = 1; off < 256; off <<= 1) {
        unsigned x = (t >= off) ? s[t - off] : 0u;
        __syncthreads();
        s[t] += x;
        __syncthreads();
    }
    const unsigned ex = s[t] - tsum;
    start[2 * t] = ex;          cur[2 * t] = ex;
    start[2 * t + 1] = ex + v0; cur[2 * t + 1] = ex + v0;
    __syncthreads();
    for (unsigned i = t; i < cnt; i += 256) {
        const unsigned p = mybuf[i];
        const unsigned pos = atomicAdd(&cur[p >> 17], 1u);
        lcsr[pos] = (int)(p & 0x1FFFFu);
    }
    __syncthreads();
    for (unsigned i = t; i < cnt; i += 256) csr[gbase + i] = lcsr[i];
    const int n0 = b * NODES_PER_BUCK;
#pragma unroll
    for (int i = t; i < NODES_PER_BUCK; i += 256) {
        const int n = n0 + i;
        if (n < N_NODES) {
            const unsigned d = hist[i];
            deg[n] = d;
            rowstart[n] = gbase + start[i];
            dinv[n] = rsqrtf((float)d + 1.0f);
        }
    }
}

__device__ __forceinline__ float4 fma4(float s, float4 w, float4 a) {
    a.x = fmaf(s, w.x, a.x);
    a.y = fmaf(s, w.y, a.y);
    a.z = fmaf(s, w.z, a.z);
    a.w = fmaf(s, w.w, a.w);
    return a;
}

// y1 = (x @ W1) * dinv.  128 nodes/block, 4x4 register tile per thread.
// thread: cg = t&7 (channels cg*4..+3), ng = t>>3; nodes = node0 + ng + 32*i.
__global__ __launch_bounds__(256) void gemm1_kernel(
        const float* __restrict__ x, const float* __restrict__ W1,
        const float* __restrict__ dinv, float* __restrict__ y1) {
    __shared__ float4 w4[IN_CH * 8];   // [k][cg]  32 KB
    __shared__ float4 xs4[128 * 9];    // [r][kq], pitch 9 -> conflict-free  18 KB
    const int t = threadIdx.x;

    const float4* W1v = (const float4*)W1;
#pragma unroll
    for (int i = 0; i < 8; i++) w4[t + i * 256] = W1v[t + i * 256];

    const int node0 = blockIdx.x * 128;
    const int cg = t & 7;
    const int ng = t >> 3;
    const float4* xv = (const float4*)x;

    float4 acc0 = {0, 0, 0, 0}, acc1 = {0, 0, 0, 0},
           acc2 = {0, 0, 0, 0}, acc3 = {0, 0, 0, 0};

#pragma unroll 1
    for (int kt = 0; kt < 8; kt++) {
        __syncthreads();
#pragma unroll
        for (int i = 0; i < 4; i++) {
            const int idx = t + i * 256;
            const int r = idx >> 3, kq = idx & 7;
            int gr = node0 + r; if (gr >= N_NODES) gr = N_NODES - 1;
            xs4[r * 9 + kq] = xv[(size_t)gr * 64 + kt * 8 + kq];
        }
        __syncthreads();
#pragma unroll
        for (int kq = 0; kq < 8; kq++) {
            const float4 xa = xs4[(ng + 0) * 9 + kq];
            const float4 xb = xs4[(ng + 32) * 9 + kq];
            const float4 xc = xs4[(ng + 64) * 9 + kq];
            const float4 xd = xs4[(ng + 96) * 9 + kq];
            const int kb = (kt * 32 + kq * 4) * 8 + cg;
            const float4 w0 = w4[kb];
            const float4 w1 = w4[kb + 8];
            const float4 w2 = w4[kb + 16];
            const float4 w3 = w4[kb + 24];
            acc0 = fma4(xa.x, w0, acc0); acc0 = fma4(xa.y, w1, acc0);
            acc0 = fma4(xa.z, w2, acc0); acc0 = fma4(xa.w, w3, acc0);
            acc1 = fma4(xb.x, w0, acc1); acc1 = fma4(xb.y, w1, acc1);
            acc1 = fma4(xb.z, w2, acc1); acc1 = fma4(xb.w, w3, acc1);
            acc2 = fma4(xc.x, w0, acc2); acc2 = fma4(xc.y, w1, acc2);
            acc2 = fma4(xc.z, w2, acc2); acc2 = fma4(xc.w, w3, acc2);
            acc3 = fma4(xd.x, w0, acc3); acc3 = fma4(xd.y, w1, acc3);
            acc3 = fma4(xd.z, w2, acc3); acc3 = fma4(xd.w, w3, acc3);
        }
    }

    float4* y1v = (float4*)y1;
#pragma unroll
    for (int i = 0; i < 4; i++) {
        const int n = node0 + ng + i * 32;
        if (n < N_NODES) {
            const float dv = dinv[n];
            float4 a = (i == 0) ? acc0 : (i == 1) ? acc1 : (i == 2) ? acc2 : acc3;
            a.x *= dv; a.y *= dv; a.z *= dv; a.w *= dv;
            y1v[(size_t)n * 8 + cg] = a;
        }
    }
}

// agg1[n] = y1[n] + sum_{s in N(n)} y1[s] ; 32 lanes per node, 4 edges in flight
__global__ __launch_bounds__(256) void gather32_kernel(
        const unsigned* __restrict__ rowstart, const unsigned* __restrict__ deg,
        const int* __restrict__ csr, const float* __restrict__ y,
        float* __restrict__ agg) {
    const int t = threadIdx.x;
    const int node = blockIdx.x * 8 + (t >> 5);
    if (node >= N_NODES) return;
    const int lane = t & 31;
    const unsigned cnt = deg[node];
    const unsigned base = rowstart[node];
    float acc = y[(size_t)node * HID_CH + lane];  // self-loop
    unsigned j = 0;
    for (; j + 4 <= cnt; j += 4) {
        const int s0 = csr[base + j];
        const int s1 = csr[base + j + 1];
        const int s2 = csr[base + j + 2];
        const int s3 = csr[base + j + 3];
        const float a0 = y[(size_t)s0 * HID_CH + lane];
        const float a1 = y[(size_t)s1 * HID_CH + lane];
        const float a2 = y[(size_t)s2 * HID_CH + lane];
        const float a3 = y[(size_t)s3 * HID_CH + lane];
        acc += a0 + a1 + a2 + a3;
    }
    for (; j < cnt; j++) acc += y[(size_t)csr[base + j] * HID_CH + lane];
    agg[(size_t)node * HID_CH + lane] = acc;
}

// agg2[n] = y2[n] + sum y2[s] ; 8 lanes per node, 4 edges in flight
__global__ __launch_bounds__(256) void gather8_kernel(
        const unsigned* __restrict__ rowstart, const unsigned* __restrict__ deg,
        const int* __restrict__ csr, const float* __restrict__ y,
        float* __restrict__ agg) {
    const int t = threadIdx.x;
    const int node = blockIdx.x * 32 + (t >> 3);
    if (node >= N_NODES) return;
    const int lane = t & 7;
    const unsigned cnt = deg[node];
    const unsigned base = rowstart[node];
    float acc = y[(size_t)node * OUT_CH + lane];
    unsigned j = 0;
    for (; j + 4 <= cnt; j += 4) {
        const int s0 = csr[base + j];
        const int s1 = csr[base + j + 1];
        const int s2 = csr[base + j + 2];
        const int s3 = csr[base + j + 3];
        const float a0 = y[(size_t)s0 * OUT_CH + lane];
        const float a1 = y[(size_t)s1 * OUT_CH + lane];
        const float a2 = y[(size_t)s2 * OUT_CH + lane];
        const float a3 = y[(size_t)s3 * OUT_CH + lane];
        acc += a0 + a1 + a2 + a3;
    }
    for (; j < cnt; j++) acc += y[(size_t)csr[base + j] * OUT_CH + lane];
    agg[(size_t)node * OUT_CH + lane] = acc;
}

// h = relu(agg1*dinv + b1); y2 = (h @ W2) * dinv
__global__ __launch_bounds__(256) void layer2_kernel(
        const float* __restrict__ agg1, const float* __restrict__ dinv,
        const float* __restrict__ b1, const float* __restrict__ W2,
        float* __restrict__ y2) {
    __shared__ float w2s[HID_CH * OUT_CH];
    __shared__ float b1s[HID_CH];
    const int t = threadIdx.x;
    if (t < HID_CH * OUT_CH) w2s[t] = W2[t];
    if (t < HID_CH) b1s[t] = b1[t];
    __syncthreads();

    const int n = blockIdx.x * blockDim.x + t;
    if (n >= N_NODES) return;
    const float dv = dinv[n];

    float h[HID_CH];
    const float4* a4 = (const float4*)(agg1 + (size_t)n * HID_CH);
#pragma unroll
    for (int i = 0; i < 8; i++) {
        float4 v = a4[i];
        h[i * 4 + 0] = fmaxf(v.x * dv + b1s[i * 4 + 0], 0.0f);
        h[i * 4 + 1] = fmaxf(v.y * dv + b1s[i * 4 + 1], 0.0f);
        h[i * 4 + 2] = fmaxf(v.z * dv + b1s[i * 4 + 2], 0.0f);
        h[i * 4 + 3] = fmaxf(v.w * dv + b1s[i * 4 + 3], 0.0f);
    }
    float o[OUT_CH] = {0, 0, 0, 0, 0, 0, 0, 0};
#pragma unroll
    for (int k = 0; k < HID_CH; k++) {
        const float hk = h[k];
#pragma unroll
        for (int c = 0; c < OUT_CH; c++) o[c] = fmaf(hk, w2s[k * OUT_CH + c], o[c]);
    }
#pragma unroll
    for (int c = 0; c < OUT_CH; c++)
        y2[(size_t)n * OUT_CH + c] = o[c] * dv;
}

// o = relu(agg2*dinv + b2); per-graph partial sums via LDS, then global atomics
__global__ __launch_bounds__(256) void pool_kernel(
        const float* __restrict__ agg2, const float* __restrict__ dinv,
        const float* __restrict__ b2, const int* __restrict__ batch,
        float* __restrict__ psum, float* __restrict__ pcnt) {
    __shared__ float ls[N_GRAPHS * OUT_CH];
    __shared__ float lc[N_GRAPHS];
    __shared__ float b2s[OUT_CH];
    const int t = threadIdx.x;
    ls[t] = 0.0f; ls[t + 256] = 0.0f;
    if (t < N_GRAPHS) lc[t] = 0.0f;
    if (t < OUT_CH) b2s[t] = b2[t];
    __syncthreads();

    const int n = blockIdx.x * blockDim.x + t;
    if (n < N_NODES) {
        const int g = batch[n];
        const float dv = dinv[n];
#pragma unroll
        for (int c = 0; c < OUT_CH; c++) {
            const float o = fmaxf(agg2[(size_t)n * OUT_CH + c] * dv + b2s[c], 0.0f);
            atomicAdd(&ls[g * OUT_CH + c], o);
        }
        atomicAdd(&lc[g], 1.0f);
    }
    __syncthreads();
    if (t < N_GRAPHS * OUT_CH) {
        const int g = t >> 3;
        if (lc[g] > 0.0f) atomicAdd(&psum[t], ls[t]);
    }
    if (t < N_GRAPHS && lc[t] > 0.0f) atomicAdd(&pcnt[t], lc[t]);
}

__global__ void logsoftmax_kernel(const float* __restrict__ psum,
                                  const float* __restrict__ pcnt,
                                  float* __restrict__ out) {
    const int g = threadIdx.x;
    if (g >= N_GRAPHS) return;
    const float cnt = fmaxf(pcnt[g], 1.0f);
    float p[OUT_CH];
    float m = -INFINITY;
#pragma unroll
    for (int c = 0; c < OUT_CH; c++) {
        p[c] = psum[g * OUT_CH + c] / cnt;
        m = fmaxf(m, p[c]);
    }
    float s = 0.0f;
#pragma unroll
    for (int c = 0; c < OUT_CH; c++) s += expf(p[c] - m);
    const float lse = logf(s);
#pragma unroll
    for (int c = 0; c < OUT_CH; c++) out[g * OUT_CH + c] = p[c] - m - lse;
}

extern "C" void kernel_launch(void* const* d_in, const int* in_sizes, int n_in,
                              void* d_out, int out_size, void* d_ws, size_t ws_size,
                              hipStream_t stream) {
    const float* x    = (const float*)d_in[0];
    const int* eidx   = (const int*)d_in[1];
    const int* batch  = (const int*)d_in[2];
    const float* W1   = (const float*)d_in[3];
    const float* b1   = (const float*)d_in[4];
    const float* W2   = (const float*)d_in[5];
    const float* b2   = (const float*)d_in[6];
    float* out = (float*)d_out;

    const int* src = eidx;
    const int* dst = eidx + N_EDGES;

    char* wsb = (char*)d_ws;
    unsigned* deg   = (unsigned*)(wsb) + OFF_DEG;
    float*    dinv  = (float*)(wsb) + OFF_DINV;
    unsigned* rows  = (unsigned*)(wsb) + OFF_ROWS;
    unsigned* cntg  = (unsigned*)(wsb) + OFF_CNTG;
    unsigned* bst   = (unsigned*)(wsb) + OFF_BSTART;
    int*      csr   = (int*)(wsb) + OFF_CSR;
    float*    y1    = (float*)(wsb) + OFF_Y1;
    float*    agg1  = (float*)(wsb) + OFF_AGG1;
    float*    y2    = (float*)(wsb) + OFF_Y2;
    float*    agg2  = (float*)(wsb) + OFF_AGG2;
    float*    psum  = (float*)(wsb) + OFF_PSUM;
    float*    pcnt  = (float*)(wsb) + OFF_PCNT;
    unsigned* bbuf  = (unsigned*)agg1;          // arena aliases agg1

    hipMemsetAsync(cntg, 0, NBUCK * sizeof(unsigned), stream);
    hipMemsetAsync(psum, 0, (N_GRAPHS * OUT_CH + N_GRAPHS) * sizeof(float), stream);

    p1_partition<<<NBLK_P1, 256, 0, stream>>>(src, dst, cntg, bbuf);
    scanb_kernel<<<1, 64, 0, stream>>>(cntg, bst);
    p2_build<<<NBUCK, 256, 0, stream>>>(cntg, bst, bbuf, csr, deg, rows, dinv);
    gemm1_kernel<<<(N_NODES + 127) / 128, 256, 0, stream>>>(x, W1, dinv, y1);
    gather32_kernel<<<(N_NODES + 7) / 8, 256, 0, stream>>>(rows, deg, csr, y1, agg1);
    layer2_kernel<<<(N_NODES + 255) / 256, 256, 0, stream>>>(agg1, dinv, b1, W2, y2);
    gather8_kernel<<<(N_NODES + 31) / 32, 256, 0, stream>>>(rows, deg, csr, y2, agg2);
    pool_kernel<<<(N_NODES + 255) / 256, 256, 0, stream>>>(agg2, dinv, b2, batch, psum, pcnt);
    logsoftmax_kernel<<<1, 64, 0, stream>>>(psum, pcnt, out);
}

// Round 5
// 183.310 us; speedup vs baseline: 2.4268x; 1.0109x over previous
//
#include <hip/hip_runtime.h>
#include <hip/hip_bf16.h>
#include <math.h>

#define N_NODES 100000
#define N_EDGES 1600000
#define IN_CH 256
#define HID_CH 32
#define OUT_CH 8
#define N_GRAPHS 64

// bucket sort params
#define BUCK_SHIFT 9
#define NODES_PER_BUCK 512
#define NBUCK ((N_NODES + NODES_PER_BUCK - 1) / NODES_PER_BUCK)   // 196
#define CAP 10240
#define CHUNK 8192
#define NBLK_P1 ((N_EDGES + CHUNK - 1) / CHUNK)                   // 196

// ---------------- workspace layout (in 4-byte words) ----------------
#define OFF_DEG    0                                // uint[N]
#define OFF_DINV   (OFF_DEG + N_NODES)              // float[N]
#define OFF_ROWS   (OFF_DINV + N_NODES)             // uint[N] row start
#define OFF_CNTG   (OFF_ROWS + N_NODES)             // uint[NBUCK]
#define OFF_BSTART (OFF_CNTG + NBUCK)               // uint[NBUCK]
#define OFF_CSR    (OFF_BSTART + NBUCK)             // int[E]
#define OFF_Y1     (OFF_CSR + N_EDGES)              // float[N*32]
#define OFF_AGG1   (OFF_Y1 + N_NODES*HID_CH)        // float[N*32]  (bbuf aliases here)
#define OFF_Y2     (OFF_AGG1 + N_NODES*HID_CH)      // float[N*8]
#define OFF_AGG2   (OFF_Y2 + N_NODES*OUT_CH)        // float[N*8]
#define OFF_PSUM   (OFF_AGG2 + N_NODES*OUT_CH)      // float[64*8]
#define OFF_PCNT   (OFF_PSUM + N_GRAPHS*OUT_CH)     // float[64]

// zero the small control buffers (replaces 2x hipMemsetAsync, each ~57us!)
__global__ void zero_kernel(unsigned* __restrict__ cntg, float* __restrict__ psum) {
    const int t = threadIdx.x;
    if (t < NBUCK) cntg[t] = 0u;
    // psum[512] + pcnt[64] are contiguous
    psum[t] = 0.0f;
    psum[t + 256] = 0.0f;
    if (t < N_GRAPHS) psum[N_GRAPHS * OUT_CH + t] = 0.0f;
}

// pass 1: partition edges into per-bucket arenas, packed (src | dlow<<17)
__global__ __launch_bounds__(256) void p1_partition(
        const int* __restrict__ src, const int* __restrict__ dst,
        unsigned* __restrict__ cntg, unsigned* __restrict__ bbuf) {
    __shared__ unsigned hcnt[NBUCK];
    __shared__ unsigned hcur[NBUCK];
    const int t = threadIdx.x;
    const long long e0 = (long long)blockIdx.x * CHUNK;

    for (int i = t; i < NBUCK; i += 256) hcnt[i] = 0;
    __syncthreads();
#pragma unroll
    for (int i = 0; i < CHUNK / 256; i++) {
        const long long e = e0 + t + i * 256;
        if (e < N_EDGES) atomicAdd(&hcnt[((unsigned)dst[e]) >> BUCK_SHIFT], 1u);
    }
    __syncthreads();
    for (int i = t; i < NBUCK; i += 256) {
        const unsigned c = hcnt[i];
        const unsigned r = c ? atomicAdd(&cntg[i], c) : 0u;
        hcur[i] = (unsigned)i * CAP + r;
    }
    __syncthreads();
#pragma unroll
    for (int i = 0; i < CHUNK / 256; i++) {
        const long long e = e0 + t + i * 256;
        if (e < N_EDGES) {
            const unsigned d = (unsigned)dst[e];
            const unsigned b = d >> BUCK_SHIFT;
            const unsigned pos = atomicAdd(&hcur[b], 1u);
            if (pos - b * CAP < CAP)
                bbuf[pos] = (unsigned)src[e] | ((d & (NODES_PER_BUCK - 1)) << 17);
        }
    }
}

__global__ void scanb_kernel(const unsigned* __restrict__ cntg,
                             unsigned* __restrict__ bstart) {
    if (threadIdx.x == 0) {
        unsigned run = 0;
        for (int i = 0; i < NBUCK; i++) {
            unsigned c = cntg[i]; if (c > CAP) c = CAP;
            bstart[i] = run;
            run += c;
        }
    }
}

// pass 2: per bucket, build node-grouped CSR in LDS, flush coalesced
__global__ __launch_bounds__(256) void p2_build(
        const unsigned* __restrict__ cntg, const unsigned* __restrict__ bstart,
        const unsigned* __restrict__ bbuf, int* __restrict__ csr,
        unsigned* __restrict__ deg, unsigned* __restrict__ rowstart,
        float* __restrict__ dinv) {
    __shared__ unsigned hist[NODES_PER_BUCK];
    __shared__ unsigned start[NODES_PER_BUCK];
    __shared__ unsigned cur[NODES_PER_BUCK];
    __shared__ unsigned s[256];
    __shared__ int lcsr[CAP];
    const int b = blockIdx.x;
    const int t = threadIdx.x;
    unsigned cnt = cntg[b]; if (cnt > CAP) cnt = CAP;
    const unsigned gbase = bstart[b];
    const unsigned* mybuf = bbuf + (size_t)b * CAP;

    hist[t] = 0; hist[t + 256] = 0;
    __syncthreads();
    for (unsigned i = t; i < cnt; i += 256) atomicAdd(&hist[mybuf[i] >> 17], 1u);
    __syncthreads();
    const unsigned v0 = hist[2 * t], v1 = hist[2 * t + 1];
    const unsigned tsum = v0 + v1;
    s[t] = tsum;
    __syncthreads();
    for (int off = 1; off < 256; off <<= 1) {
        unsigned x = (t >= off) ? s[t - off] : 0u;
        __syncthreads();
        s[t] += x;
        __syncthreads();
    }
    const unsigned ex = s[t] - tsum;
    start[2 * t] = ex;          cur[2 * t] = ex;
    start[2 * t + 1] = ex + v0; cur[2 * t + 1] = ex + v0;
    __syncthreads();
    for (unsigned i = t; i < cnt; i += 256) {
        const unsigned p = mybuf[i];
        const unsigned pos = atomicAdd(&cur[p >> 17], 1u);
        lcsr[pos] = (int)(p & 0x1FFFFu);
    }
    __syncthreads();
    for (unsigned i = t; i < cnt; i += 256) csr[gbase + i] = lcsr[i];
    const int n0 = b * NODES_PER_BUCK;
#pragma unroll
    for (int i = t; i < NODES_PER_BUCK; i += 256) {
        const int n = n0 + i;
        if (n < N_NODES) {
            const unsigned d = hist[i];
            deg[n] = d;
            rowstart[n] = gbase + start[i];
            dinv[n] = rsqrtf((float)d + 1.0f);
        }
    }
}

__device__ __forceinline__ float4 fma4(float s, float4 w, float4 a) {
    a.x = fmaf(s, w.x, a.x);
    a.y = fmaf(s, w.y, a.y);
    a.z = fmaf(s, w.z, a.z);
    a.w = fmaf(s, w.w, a.w);
    return a;
}

// y1 = (x @ W1) * dinv.  128 nodes/block, 4x4 register tile per thread.
__global__ __launch_bounds__(256) void gemm1_kernel(
        const float* __restrict__ x, const float* __restrict__ W1,
        const float* __restrict__ dinv, float* __restrict__ y1) {
    __shared__ float4 w4[IN_CH * 8];   // [k][cg]  32 KB
    __shared__ float4 xs4[128 * 9];    // [r][kq], pitch 9 -> conflict-free  18 KB
    const int t = threadIdx.x;

    const float4* W1v = (const float4*)W1;
#pragma unroll
    for (int i = 0; i < 8; i++) w4[t + i * 256] = W1v[t + i * 256];

    const int node0 = blockIdx.x * 128;
    const int cg = t & 7;
    const int ng = t >> 3;
    const float4* xv = (const float4*)x;

    float4 acc0 = {0, 0, 0, 0}, acc1 = {0, 0, 0, 0},
           acc2 = {0, 0, 0, 0}, acc3 = {0, 0, 0, 0};

#pragma unroll 1
    for (int kt = 0; kt < 8; kt++) {
        __syncthreads();
#pragma unroll
        for (int i = 0; i < 4; i++) {
            const int idx = t + i * 256;
            const int r = idx >> 3, kq = idx & 7;
            int gr = node0 + r; if (gr >= N_NODES) gr = N_NODES - 1;
            xs4[r * 9 + kq] = xv[(size_t)gr * 64 + kt * 8 + kq];
        }
        __syncthreads();
#pragma unroll
        for (int kq = 0; kq < 8; kq++) {
            const float4 xa = xs4[(ng + 0) * 9 + kq];
            const float4 xb = xs4[(ng + 32) * 9 + kq];
            const float4 xc = xs4[(ng + 64) * 9 + kq];
            const float4 xd = xs4[(ng + 96) * 9 + kq];
            const int kb = (kt * 32 + kq * 4) * 8 + cg;
            const float4 w0 = w4[kb];
            const float4 w1 = w4[kb + 8];
            const float4 w2 = w4[kb + 16];
            const float4 w3 = w4[kb + 24];
            acc0 = fma4(xa.x, w0, acc0); acc0 = fma4(xa.y, w1, acc0);
            acc0 = fma4(xa.z, w2, acc0); acc0 = fma4(xa.w, w3, acc0);
            acc1 = fma4(xb.x, w0, acc1); acc1 = fma4(xb.y, w1, acc1);
            acc1 = fma4(xb.z, w2, acc1); acc1 = fma4(xb.w, w3, acc1);
            acc2 = fma4(xc.x, w0, acc2); acc2 = fma4(xc.y, w1, acc2);
            acc2 = fma4(xc.z, w2, acc2); acc2 = fma4(xc.w, w3, acc2);
            acc3 = fma4(xd.x, w0, acc3); acc3 = fma4(xd.y, w1, acc3);
            acc3 = fma4(xd.z, w2, acc3); acc3 = fma4(xd.w, w3, acc3);
        }
    }

    float4* y1v = (float4*)y1;
#pragma unroll
    for (int i = 0; i < 4; i++) {
        const int n = node0 + ng + i * 32;
        if (n < N_NODES) {
            const float dv = dinv[n];
            float4 a = (i == 0) ? acc0 : (i == 1) ? acc1 : (i == 2) ? acc2 : acc3;
            a.x *= dv; a.y *= dv; a.z *= dv; a.w *= dv;
            y1v[(size_t)n * 8 + cg] = a;
        }
    }
}

// agg1[n] = y1[n] + sum_{s in N(n)} y1[s] ; 32 lanes per node, 4 edges in flight
__global__ __launch_bounds__(256) void gather32_kernel(
        const unsigned* __restrict__ rowstart, const unsigned* __restrict__ deg,
        const int* __restrict__ csr, const float* __restrict__ y,
        float* __restrict__ agg) {
    const int t = threadIdx.x;
    const int node = blockIdx.x * 8 + (t >> 5);
    if (node >= N_NODES) return;
    const int lane = t & 31;
    const unsigned cnt = deg[node];
    const unsigned base = rowstart[node];
    float acc = y[(size_t)node * HID_CH + lane];  // self-loop
    unsigned j = 0;
    for (; j + 4 <= cnt; j += 4) {
        const int s0 = csr[base + j];
        const int s1 = csr[base + j + 1];
        const int s2 = csr[base + j + 2];
        const int s3 = csr[base + j + 3];
        const float a0 = y[(size_t)s0 * HID_CH + lane];
        const float a1 = y[(size_t)s1 * HID_CH + lane];
        const float a2 = y[(size_t)s2 * HID_CH + lane];
        const float a3 = y[(size_t)s3 * HID_CH + lane];
        acc += a0 + a1 + a2 + a3;
    }
    for (; j < cnt; j++) acc += y[(size_t)csr[base + j] * HID_CH + lane];
    agg[(size_t)node * HID_CH + lane] = acc;
}

// agg2[n] = y2[n] + sum y2[s] ; 8 lanes per node, 4 edges in flight
__global__ __launch_bounds__(256) void gather8_kernel(
        const unsigned* __restrict__ rowstart, const unsigned* __restrict__ deg,
        const int* __restrict__ csr, const float* __restrict__ y,
        float* __restrict__ agg) {
    const int t = threadIdx.x;
    const int node = blockIdx.x * 32 + (t >> 3);
    if (node >= N_NODES) return;
    const int lane = t & 7;
    const unsigned cnt = deg[node];
    const unsigned base = rowstart[node];
    float acc = y[(size_t)node * OUT_CH + lane];
    unsigned j = 0;
    for (; j + 4 <= cnt; j += 4) {
        const int s0 = csr[base + j];
        const int s1 = csr[base + j + 1];
        const int s2 = csr[base + j + 2];
        const int s3 = csr[base + j + 3];
        const float a0 = y[(size_t)s0 * OUT_CH + lane];
        const float a1 = y[(size_t)s1 * OUT_CH + lane];
        const float a2 = y[(size_t)s2 * OUT_CH + lane];
        const float a3 = y[(size_t)s3 * OUT_CH + lane];
        acc += a0 + a1 + a2 + a3;
    }
    for (; j < cnt; j++) acc += y[(size_t)csr[base + j] * OUT_CH + lane];
    agg[(size_t)node * OUT_CH + lane] = acc;
}

// h = relu(agg1*dinv + b1); y2 = (h @ W2) * dinv
__global__ __launch_bounds__(256) void layer2_kernel(
        const float* __restrict__ agg1, const float* __restrict__ dinv,
        const float* __restrict__ b1, const float* __restrict__ W2,
        float* __restrict__ y2) {
    __shared__ float w2s[HID_CH * OUT_CH];
    __shared__ float b1s[HID_CH];
    const int t = threadIdx.x;
    if (t < HID_CH * OUT_CH) w2s[t] = W2[t];
    if (t < HID_CH) b1s[t] = b1[t];
    __syncthreads();

    const int n = blockIdx.x * blockDim.x + t;
    if (n >= N_NODES) return;
    const float dv = dinv[n];

    float h[HID_CH];
    const float4* a4 = (const float4*)(agg1 + (size_t)n * HID_CH);
#pragma unroll
    for (int i = 0; i < 8; i++) {
        float4 v = a4[i];
        h[i * 4 + 0] = fmaxf(v.x * dv + b1s[i * 4 + 0], 0.0f);
        h[i * 4 + 1] = fmaxf(v.y * dv + b1s[i * 4 + 1], 0.0f);
        h[i * 4 + 2] = fmaxf(v.z * dv + b1s[i * 4 + 2], 0.0f);
        h[i * 4 + 3] = fmaxf(v.w * dv + b1s[i * 4 + 3], 0.0f);
    }
    float o[OUT_CH] = {0, 0, 0, 0, 0, 0, 0, 0};
#pragma unroll
    for (int k = 0; k < HID_CH; k++) {
        const float hk = h[k];
#pragma unroll
        for (int c = 0; c < OUT_CH; c++) o[c] = fmaf(hk, w2s[k * OUT_CH + c], o[c]);
    }
#pragma unroll
    for (int c = 0; c < OUT_CH; c++)
        y2[(size_t)n * OUT_CH + c] = o[c] * dv;
}

// o = relu(agg2*dinv + b2); per-graph partial sums via LDS, then global atomics
__global__ __launch_bounds__(256) void pool_kernel(
        const float* __restrict__ agg2, const float* __restrict__ dinv,
        const float* __restrict__ b2, const int* __restrict__ batch,
        float* __restrict__ psum, float* __restrict__ pcnt) {
    __shared__ float ls[N_GRAPHS * OUT_CH];
    __shared__ float lc[N_GRAPHS];
    __shared__ float b2s[OUT_CH];
    const int t = threadIdx.x;
    ls[t] = 0.0f; ls[t + 256] = 0.0f;
    if (t < N_GRAPHS) lc[t] = 0.0f;
    if (t < OUT_CH) b2s[t] = b2[t];
    __syncthreads();

    const int n = blockIdx.x * blockDim.x + t;
    if (n < N_NODES) {
        const int g = batch[n];
        const float dv = dinv[n];
#pragma unroll
        for (int c = 0; c < OUT_CH; c++) {
            const float o = fmaxf(agg2[(size_t)n * OUT_CH + c] * dv + b2s[c], 0.0f);
            atomicAdd(&ls[g * OUT_CH + c], o);
        }
        atomicAdd(&lc[g], 1.0f);
    }
    __syncthreads();
    if (t < N_GRAPHS * OUT_CH) {
        const int g = t >> 3;
        if (lc[g] > 0.0f) atomicAdd(&psum[t], ls[t]);
    }
    if (t < N_GRAPHS && lc[t] > 0.0f) atomicAdd(&pcnt[t], lc[t]);
}

__global__ void logsoftmax_kernel(const float* __restrict__ psum,
                                  const float* __restrict__ pcnt,
                                  float* __restrict__ out) {
    const int g = threadIdx.x;
    if (g >= N_GRAPHS) return;
    const float cnt = fmaxf(pcnt[g], 1.0f);
    float p[OUT_CH];
    float m = -INFINITY;
#pragma unroll
    for (int c = 0; c < OUT_CH; c++) {
        p[c] = psum[g * OUT_CH + c] / cnt;
        m = fmaxf(m, p[c]);
    }
    float s = 0.0f;
#pragma unroll
    for (int c = 0; c < OUT_CH; c++) s += expf(p[c] - m);
    const float lse = logf(s);
#pragma unroll
    for (int c = 0; c < OUT_CH; c++) out[g * OUT_CH + c] = p[c] - m - lse;
}

extern "C" void kernel_launch(void* const* d_in, const int* in_sizes, int n_in,
                              void* d_out, int out_size, void* d_ws, size_t ws_size,
                              hipStream_t stream) {
    const float* x    = (const float*)d_in[0];
    const int* eidx   = (const int*)d_in[1];
    const int* batch  = (const int*)d_in[2];
    const float* W1   = (const float*)d_in[3];
    const float* b1   = (const float*)d_in[4];
    const float* W2   = (const float*)d_in[5];
    const float* b2   = (const float*)d_in[6];
    float* out = (float*)d_out;

    const int* src = eidx;
    const int* dst = eidx + N_EDGES;

    char* wsb = (char*)d_ws;
    unsigned* deg   = (unsigned*)(wsb) + OFF_DEG;
    float*    dinv  = (float*)(wsb) + OFF_DINV;
    unsigned* rows  = (unsigned*)(wsb) + OFF_ROWS;
    unsigned* cntg  = (unsigned*)(wsb) + OFF_CNTG;
    unsigned* bst   = (unsigned*)(wsb) + OFF_BSTART;
    int*      csr   = (int*)(wsb) + OFF_CSR;
    float*    y1    = (float*)(wsb) + OFF_Y1;
    float*    agg1  = (float*)(wsb) + OFF_AGG1;
    float*    y2    = (float*)(wsb) + OFF_Y2;
    float*    agg2  = (float*)(wsb) + OFF_AGG2;
    float*    psum  = (float*)(wsb) + OFF_PSUM;
    float*    pcnt  = (float*)(wsb) + OFF_PCNT;
    unsigned* bbuf  = (unsigned*)agg1;          // arena aliases agg1

    zero_kernel<<<1, 256, 0, stream>>>(cntg, psum);
    p1_partition<<<NBLK_P1, 256, 0, stream>>>(src, dst, cntg, bbuf);
    scanb_kernel<<<1, 64, 0, stream>>>(cntg, bst);
    p2_build<<<NBUCK, 256, 0, stream>>>(cntg, bst, bbuf, csr, deg, rows, dinv);
    gemm1_kernel<<<(N_NODES + 127) / 128, 256, 0, stream>>>(x, W1, dinv, y1);
    gather32_kernel<<<(N_NODES + 7) / 8, 256, 0, stream>>>(rows, deg, csr, y1, agg1);
    layer2_kernel<<<(N_NODES + 255) / 256, 256, 0, stream>>>(agg1, dinv, b1, W2, y2);
    gather8_kernel<<<(N_NODES + 31) / 32, 256, 0, stream>>>(rows, deg, csr, y2, agg2);
    pool_kernel<<<(N_NODES + 255) / 256, 256, 0, stream>>>(agg2, dinv, b2, batch, psum, pcnt);
    logsoftmax_kernel<<<1, 64, 0, stream>>>(psum, pcnt, out);
}

// Round 6
// 180.762 us; speedup vs baseline: 2.4610x; 1.0141x over previous
//
#include <hip/hip_runtime.h>
#include <hip/hip_bf16.h>
#include <math.h>

#define N_NODES 100000
#define N_EDGES 1600000
#define IN_CH 256
#define HID_CH 32
#define OUT_CH 8
#define N_GRAPHS 64

// bucket sort params
#define BUCK_SHIFT 9
#define NODES_PER_BUCK 512
#define NBUCK ((N_NODES + NODES_PER_BUCK - 1) / NODES_PER_BUCK)   // 196
#define CAP 10240
#define CHUNK 8192
#define NBLK_P1 ((N_EDGES + CHUNK - 1) / CHUNK)                   // 196

// ---------------- workspace layout (in 4-byte words) ----------------
#define OFF_DEG    0                                // uint[N]
#define OFF_DINV   (OFF_DEG + N_NODES)              // float[N]
#define OFF_ROWS   (OFF_DINV + N_NODES)             // uint[N]
#define OFF_CNTG   (OFF_ROWS + N_NODES)             // uint[NBUCK]
#define OFF_CSR    (OFF_CNTG + NBUCK)               // int[E]
#define OFF_Y1     (OFF_CSR + N_EDGES)              // float[N*32]
#define OFF_BBUF   (OFF_Y1 + N_NODES*HID_CH)        // uint[NBUCK*CAP]
#define OFF_Y2     (OFF_BBUF + NBUCK*CAP)           // float[N*8]
#define OFF_PSUM   (OFF_Y2 + N_NODES*OUT_CH)        // float[64*8]
#define OFF_PCNT   (OFF_PSUM + N_GRAPHS*OUT_CH)     // float[64]

// zero the bucket counters (must be 0 before p1 every call)
__global__ void zero_kernel(unsigned* __restrict__ cntg) {
    const int t = threadIdx.x;
    if (t < NBUCK) cntg[t] = 0u;
}

// pass 1: partition edges into per-bucket arenas, packed (src | dlow<<17)
__global__ __launch_bounds__(256) void p1_partition(
        const int* __restrict__ src, const int* __restrict__ dst,
        unsigned* __restrict__ cntg, unsigned* __restrict__ bbuf) {
    __shared__ unsigned hcnt[NBUCK];
    __shared__ unsigned hcur[NBUCK];
    const int t = threadIdx.x;
    const long long e0 = (long long)blockIdx.x * CHUNK;

    for (int i = t; i < NBUCK; i += 256) hcnt[i] = 0;
    __syncthreads();
#pragma unroll
    for (int i = 0; i < CHUNK / 256; i++) {
        const long long e = e0 + t + i * 256;
        if (e < N_EDGES) atomicAdd(&hcnt[((unsigned)dst[e]) >> BUCK_SHIFT], 1u);
    }
    __syncthreads();
    for (int i = t; i < NBUCK; i += 256) {
        const unsigned c = hcnt[i];
        const unsigned r = c ? atomicAdd(&cntg[i], c) : 0u;
        hcur[i] = (unsigned)i * CAP + r;
    }
    __syncthreads();
#pragma unroll
    for (int i = 0; i < CHUNK / 256; i++) {
        const long long e = e0 + t + i * 256;
        if (e < N_EDGES) {
            const unsigned d = (unsigned)dst[e];
            const unsigned b = d >> BUCK_SHIFT;
            const unsigned pos = atomicAdd(&hcur[b], 1u);
            if (pos - b * CAP < CAP)
                bbuf[pos] = (unsigned)src[e] | ((d & (NODES_PER_BUCK - 1)) << 17);
        }
    }
}

// pass 2: per bucket, compute own gbase (inline prefix over cntg), build
// node-grouped CSR in LDS, flush coalesced; emit deg/rowstart/dinv.
__global__ __launch_bounds__(256) void p2_build(
        const unsigned* __restrict__ cntg,
        const unsigned* __restrict__ bbuf, int* __restrict__ csr,
        unsigned* __restrict__ deg, unsigned* __restrict__ rowstart,
        float* __restrict__ dinv) {
    __shared__ unsigned hist[NODES_PER_BUCK];
    __shared__ unsigned start[NODES_PER_BUCK];
    __shared__ unsigned cur[NODES_PER_BUCK];
    __shared__ unsigned s[256];
    __shared__ int lcsr[CAP];
    const int b = blockIdx.x;
    const int t = threadIdx.x;

    // gbase = sum_{i<b} min(cntg[i],CAP)   (b <= 195 < 256)
    unsigned pc = 0;
    if (t < b) { pc = cntg[t]; if (pc > CAP) pc = CAP; }
    s[t] = pc;
    __syncthreads();
    for (int off = 128; off > 0; off >>= 1) {
        if (t < off) s[t] += s[t + off];
        __syncthreads();
    }
    const unsigned gbase = s[0];
    unsigned cnt = cntg[b]; if (cnt > CAP) cnt = CAP;
    const unsigned* mybuf = bbuf + (size_t)b * CAP;

    hist[t] = 0; hist[t + 256] = 0;
    __syncthreads();
    for (unsigned i = t; i < cnt; i += 256) atomicAdd(&hist[mybuf[i] >> 17], 1u);
    __syncthreads();
    const unsigned v0 = hist[2 * t], v1 = hist[2 * t + 1];
    const unsigned tsum = v0 + v1;
    s[t] = tsum;
    __syncthreads();
    for (int off = 1; off < 256; off <<= 1) {
        unsigned x = (t >= off) ? s[t - off] : 0u;
        __syncthreads();
        s[t] += x;
        __syncthreads();
    }
    const unsigned ex = s[t] - tsum;
    start[2 * t] = ex;          cur[2 * t] = ex;
    start[2 * t + 1] = ex + v0; cur[2 * t + 1] = ex + v0;
    __syncthreads();
    for (unsigned i = t; i < cnt; i += 256) {
        const unsigned p = mybuf[i];
        const unsigned pos = atomicAdd(&cur[p >> 17], 1u);
        lcsr[pos] = (int)(p & 0x1FFFFu);
    }
    __syncthreads();
    for (unsigned i = t; i < cnt; i += 256) csr[gbase + i] = lcsr[i];
    const int n0 = b * NODES_PER_BUCK;
#pragma unroll
    for (int i = t; i < NODES_PER_BUCK; i += 256) {
        const int n = n0 + i;
        if (n < N_NODES) {
            const unsigned d = hist[i];
            deg[n] = d;
            rowstart[n] = gbase + start[i];
            dinv[n] = rsqrtf((float)d + 1.0f);
        }
    }
}

__device__ __forceinline__ float4 fma4(float s, float4 w, float4 a) {
    a.x = fmaf(s, w.x, a.x);
    a.y = fmaf(s, w.y, a.y);
    a.z = fmaf(s, w.z, a.z);
    a.w = fmaf(s, w.w, a.w);
    return a;
}

// y1 = (x @ W1) * dinv.  128 nodes/block, 4x4 register tile per thread.
// block 0 also zeroes psum/pcnt (needed before g8pool).
__global__ __launch_bounds__(256) void gemm1_kernel(
        const float* __restrict__ x, const float* __restrict__ W1,
        const float* __restrict__ dinv, float* __restrict__ y1,
        float* __restrict__ psum) {
    __shared__ float4 w4[IN_CH * 8];   // [k][cg]  32 KB
    __shared__ float4 xs4[128 * 9];    // [r][kq], pitch 9  18 KB
    const int t = threadIdx.x;

    if (blockIdx.x == 0) {
        for (int i = t; i < N_GRAPHS * OUT_CH + N_GRAPHS; i += 256) psum[i] = 0.0f;
    }

    const float4* W1v = (const float4*)W1;
#pragma unroll
    for (int i = 0; i < 8; i++) w4[t + i * 256] = W1v[t + i * 256];

    const int node0 = blockIdx.x * 128;
    const int cg = t & 7;
    const int ng = t >> 3;
    const float4* xv = (const float4*)x;

    float4 acc0 = {0, 0, 0, 0}, acc1 = {0, 0, 0, 0},
           acc2 = {0, 0, 0, 0}, acc3 = {0, 0, 0, 0};

#pragma unroll 1
    for (int kt = 0; kt < 8; kt++) {
        __syncthreads();
#pragma unroll
        for (int i = 0; i < 4; i++) {
            const int idx = t + i * 256;
            const int r = idx >> 3, kq = idx & 7;
            int gr = node0 + r; if (gr >= N_NODES) gr = N_NODES - 1;
            xs4[r * 9 + kq] = xv[(size_t)gr * 64 + kt * 8 + kq];
        }
        __syncthreads();
#pragma unroll
        for (int kq = 0; kq < 8; kq++) {
            const float4 xa = xs4[(ng + 0) * 9 + kq];
            const float4 xb = xs4[(ng + 32) * 9 + kq];
            const float4 xc = xs4[(ng + 64) * 9 + kq];
            const float4 xd = xs4[(ng + 96) * 9 + kq];
            const int kb = (kt * 32 + kq * 4) * 8 + cg;
            const float4 w0 = w4[kb];
            const float4 w1 = w4[kb + 8];
            const float4 w2 = w4[kb + 16];
            const float4 w3 = w4[kb + 24];
            acc0 = fma4(xa.x, w0, acc0); acc0 = fma4(xa.y, w1, acc0);
            acc0 = fma4(xa.z, w2, acc0); acc0 = fma4(xa.w, w3, acc0);
            acc1 = fma4(xb.x, w0, acc1); acc1 = fma4(xb.y, w1, acc1);
            acc1 = fma4(xb.z, w2, acc1); acc1 = fma4(xb.w, w3, acc1);
            acc2 = fma4(xc.x, w0, acc2); acc2 = fma4(xc.y, w1, acc2);
            acc2 = fma4(xc.z, w2, acc2); acc2 = fma4(xc.w, w3, acc2);
            acc3 = fma4(xd.x, w0, acc3); acc3 = fma4(xd.y, w1, acc3);
            acc3 = fma4(xd.z, w2, acc3); acc3 = fma4(xd.w, w3, acc3);
        }
    }

    float4* y1v = (float4*)y1;
#pragma unroll
    for (int i = 0; i < 4; i++) {
        const int n = node0 + ng + i * 32;
        if (n < N_NODES) {
            const float dv = dinv[n];
            float4 a = (i == 0) ? acc0 : (i == 1) ? acc1 : (i == 2) ? acc2 : acc3;
            a.x *= dv; a.y *= dv; a.z *= dv; a.w *= dv;
            y1v[(size_t)n * 8 + cg] = a;
        }
    }
}

// fused: agg = y1[n] + sum y1[s]; h = relu(agg*dinv+b1);
// y2 = (h @ W2) * dinv  via LDS h-buffer + cross-lane reduce.
// 8 nodes/block (32 lanes per node); grid = 12500 exact.
__global__ __launch_bounds__(256) void g32l2_kernel(
        const unsigned* __restrict__ rowstart, const unsigned* __restrict__ deg,
        const int* __restrict__ csr, const float* __restrict__ y,
        const float* __restrict__ dinv, const float* __restrict__ b1,
        const float* __restrict__ W2, float* __restrict__ y2) {
    __shared__ float w2s[HID_CH][9];   // padded: conflict-free
    __shared__ float b1s[HID_CH];
    __shared__ float hbuf[8][33];
    const int t = threadIdx.x;
    { const int k = t >> 3, c = t & 7; w2s[k][c] = W2[t]; }
    if (t < HID_CH) b1s[t] = b1[t];
    __syncthreads();

    const int nl = t >> 5;
    const int node = blockIdx.x * 8 + nl;
    const int lane = t & 31;
    const unsigned cnt = deg[node];
    const unsigned base = rowstart[node];
    float acc = y[(size_t)node * HID_CH + lane];  // self-loop
    unsigned j = 0;
    for (; j + 8 <= cnt; j += 8) {
        const int s0 = csr[base + j];
        const int s1 = csr[base + j + 1];
        const int s2 = csr[base + j + 2];
        const int s3 = csr[base + j + 3];
        const int s4 = csr[base + j + 4];
        const int s5 = csr[base + j + 5];
        const int s6 = csr[base + j + 6];
        const int s7 = csr[base + j + 7];
        const float a0 = y[(size_t)s0 * HID_CH + lane];
        const float a1 = y[(size_t)s1 * HID_CH + lane];
        const float a2 = y[(size_t)s2 * HID_CH + lane];
        const float a3 = y[(size_t)s3 * HID_CH + lane];
        const float a4 = y[(size_t)s4 * HID_CH + lane];
        const float a5 = y[(size_t)s5 * HID_CH + lane];
        const float a6 = y[(size_t)s6 * HID_CH + lane];
        const float a7 = y[(size_t)s7 * HID_CH + lane];
        acc += ((a0 + a1) + (a2 + a3)) + ((a4 + a5) + (a6 + a7));
    }
    for (; j + 4 <= cnt; j += 4) {
        const int s0 = csr[base + j];
        const int s1 = csr[base + j + 1];
        const int s2 = csr[base + j + 2];
        const int s3 = csr[base + j + 3];
        const float a0 = y[(size_t)s0 * HID_CH + lane];
        const float a1 = y[(size_t)s1 * HID_CH + lane];
        const float a2 = y[(size_t)s2 * HID_CH + lane];
        const float a3 = y[(size_t)s3 * HID_CH + lane];
        acc += (a0 + a1) + (a2 + a3);
    }
    for (; j < cnt; j++) acc += y[(size_t)csr[base + j] * HID_CH + lane];

    const float dv = dinv[node];
    const float h = fmaxf(fmaf(acc, dv, b1s[lane]), 0.0f);
    hbuf[nl][lane] = h;   // same-wave producer/consumer: no barrier needed

    const int c = lane & 7;
    const int kb = (lane >> 3) * 8;   // 4 lane-groups x 8 k's = 32 k
    float p = 0.0f;
#pragma unroll
    for (int i = 0; i < 8; i++) p = fmaf(hbuf[nl][kb + i], w2s[kb + i][c], p);
    p += __shfl_xor(p, 8);
    p += __shfl_xor(p, 16);
    if (lane < 8) y2[(size_t)node * OUT_CH + lane] = p * dv;
}

// fused: agg2 = y2[n] + sum y2[s]; o = relu(agg2*dinv+b2);
// per-graph pooling via LDS accumulators; flush [gmin,gmax] only.
// 32 nodes/block (8 lanes per node); grid = 3125 exact.
__global__ __launch_bounds__(256) void g8pool_kernel(
        const unsigned* __restrict__ rowstart, const unsigned* __restrict__ deg,
        const int* __restrict__ csr, const float* __restrict__ y,
        const float* __restrict__ dinv, const float* __restrict__ b2,
        const int* __restrict__ batch,
        float* __restrict__ psum, float* __restrict__ pcnt) {
    __shared__ float ls[N_GRAPHS * OUT_CH];
    __shared__ float lc[N_GRAPHS];
    __shared__ float b2s[OUT_CH];
    __shared__ int grange[2];
    const int t = threadIdx.x;
    ls[t] = 0.0f; ls[t + 256] = 0.0f;
    if (t < N_GRAPHS) lc[t] = 0.0f;
    if (t < OUT_CH) b2s[t] = b2[t];
    if (t == 0) { grange[0] = N_GRAPHS; grange[1] = -1; }
    __syncthreads();

    const int node = blockIdx.x * 32 + (t >> 3);
    const int lane = t & 7;
    const int g = batch[node];
    const unsigned cnt = deg[node];
    const unsigned base = rowstart[node];
    float acc = y[(size_t)node * OUT_CH + lane];
    unsigned j = 0;
    for (; j + 4 <= cnt; j += 4) {
        const int s0 = csr[base + j];
        const int s1 = csr[base + j + 1];
        const int s2 = csr[base + j + 2];
        const int s3 = csr[base + j + 3];
        const float a0 = y[(size_t)s0 * OUT_CH + lane];
        const float a1 = y[(size_t)s1 * OUT_CH + lane];
        const float a2 = y[(size_t)s2 * OUT_CH + lane];
        const float a3 = y[(size_t)s3 * OUT_CH + lane];
        acc += (a0 + a1) + (a2 + a3);
    }
    for (; j < cnt; j++) acc += y[(size_t)csr[base + j] * OUT_CH + lane];

    const float o = fmaxf(fmaf(acc, dinv[node], b2s[lane]), 0.0f);
    atomicAdd(&ls[g * OUT_CH + lane], o);
    if (lane == 0) {
        atomicAdd(&lc[g], 1.0f);
        atomicMin(&grange[0], g);
        atomicMax(&grange[1], g);
    }
    __syncthreads();
    const int g0 = grange[0], g1 = grange[1];
    const int nent = (g1 - g0 + 1) * OUT_CH;
    for (int i = t; i < nent; i += 256)
        atomicAdd(&psum[g0 * OUT_CH + i], ls[g0 * OUT_CH + i]);
    for (int i = t; i < g1 - g0 + 1; i += 256)
        atomicAdd(&pcnt[g0 + i], lc[g0 + i]);
}

__global__ void logsoftmax_kernel(const float* __restrict__ psum,
                                  const float* __restrict__ pcnt,
                                  float* __restrict__ out) {
    const int g = threadIdx.x;
    if (g >= N_GRAPHS) return;
    const float cnt = fmaxf(pcnt[g], 1.0f);
    float p[OUT_CH];
    float m = -INFINITY;
#pragma unroll
    for (int c = 0; c < OUT_CH; c++) {
        p[c] = psum[g * OUT_CH + c] / cnt;
        m = fmaxf(m, p[c]);
    }
    float s = 0.0f;
#pragma unroll
    for (int c = 0; c < OUT_CH; c++) s += expf(p[c] - m);
    const float lse = logf(s);
#pragma unroll
    for (int c = 0; c < OUT_CH; c++) out[g * OUT_CH + c] = p[c] - m - lse;
}

extern "C" void kernel_launch(void* const* d_in, const int* in_sizes, int n_in,
                              void* d_out, int out_size, void* d_ws, size_t ws_size,
                              hipStream_t stream) {
    const float* x    = (const float*)d_in[0];
    const int* eidx   = (const int*)d_in[1];
    const int* batch  = (const int*)d_in[2];
    const float* W1   = (const float*)d_in[3];
    const float* b1   = (const float*)d_in[4];
    const float* W2   = (const float*)d_in[5];
    const float* b2   = (const float*)d_in[6];
    float* out = (float*)d_out;

    const int* src = eidx;
    const int* dst = eidx + N_EDGES;

    char* wsb = (char*)d_ws;
    unsigned* deg   = (unsigned*)(wsb) + OFF_DEG;
    float*    dinv  = (float*)(wsb) + OFF_DINV;
    unsigned* rows  = (unsigned*)(wsb) + OFF_ROWS;
    unsigned* cntg  = (unsigned*)(wsb) + OFF_CNTG;
    int*      csr   = (int*)(wsb) + OFF_CSR;
    float*    y1    = (float*)(wsb) + OFF_Y1;
    unsigned* bbuf  = (unsigned*)(wsb) + OFF_BBUF;
    float*    y2    = (float*)(wsb) + OFF_Y2;
    float*    psum  = (float*)(wsb) + OFF_PSUM;
    float*    pcnt  = (float*)(wsb) + OFF_PCNT;

    zero_kernel<<<1, 256, 0, stream>>>(cntg);
    p1_partition<<<NBLK_P1, 256, 0, stream>>>(src, dst, cntg, bbuf);
    p2_build<<<NBUCK, 256, 0, stream>>>(cntg, bbuf, csr, deg, rows, dinv);
    gemm1_kernel<<<(N_NODES + 127) / 128, 256, 0, stream>>>(x, W1, dinv, y1, psum);
    g32l2_kernel<<<N_NODES / 8, 256, 0, stream>>>(rows, deg, csr, y1, dinv, b1, W2, y2);
    g8pool_kernel<<<N_NODES / 32, 256, 0, stream>>>(rows, deg, csr, y2, dinv, b2, batch, psum, pcnt);
    logsoftmax_kernel<<<1, 64, 0, stream>>>(psum, pcnt, out);
}

// Round 7
// 169.586 us; speedup vs baseline: 2.6232x; 1.0659x over previous
//
#include <hip/hip_runtime.h>
#include <hip/hip_bf16.h>
#include <math.h>

#define N_NODES 100000
#define N_EDGES 1600000
#define IN_CH 256
#define HID_CH 32
#define OUT_CH 8
#define N_GRAPHS 64

// bucket sort params (256 nodes / bucket)
#define BUCK_SHIFT 8
#define NODES_PER_BUCK 256
#define NBUCK ((N_NODES + NODES_PER_BUCK - 1) / NODES_PER_BUCK)   // 391
#define CAP 4608                      // mean 4092 + 8 sigma
#define CHUNK 4096
#define NBLK_P1 ((N_EDGES + CHUNK - 1) / CHUNK)                   // 391

// ---------------- workspace layout (in 4-byte words) ----------------
#define OFF_DEG    0                                // uint[N]
#define OFF_DINV   (OFF_DEG + N_NODES)              // float[N]
#define OFF_ROWS   (OFF_DINV + N_NODES)             // uint[N]
#define OFF_CNTG   (OFF_ROWS + N_NODES)             // uint[NBUCK]
#define OFF_CSR    (OFF_CNTG + NBUCK)               // int[E]
#define OFF_Y1     (OFF_CSR + N_EDGES)              // float[N*32]
#define OFF_BBUF   (OFF_Y1 + N_NODES*HID_CH)        // uint[NBUCK*CAP]
#define OFF_Y2     (OFF_BBUF + NBUCK*CAP)           // float[N*8]
#define OFF_PSUM   (OFF_Y2 + N_NODES*OUT_CH)        // float[64*8]
#define OFF_PCNT   (OFF_PSUM + N_GRAPHS*OUT_CH)     // float[64]

__global__ void zero_kernel(unsigned* __restrict__ cntg) {
    for (int i = threadIdx.x; i < NBUCK; i += 256) cntg[i] = 0u;
}

// pass 1: partition edges into per-bucket arenas, packed (src | dlow<<17)
__global__ __launch_bounds__(256) void p1_partition(
        const int* __restrict__ src, const int* __restrict__ dst,
        unsigned* __restrict__ cntg, unsigned* __restrict__ bbuf) {
    __shared__ unsigned hcnt[NBUCK];
    __shared__ unsigned hcur[NBUCK];
    const int t = threadIdx.x;
    const long long e0 = (long long)blockIdx.x * CHUNK;

    for (int i = t; i < NBUCK; i += 256) hcnt[i] = 0;
    __syncthreads();
#pragma unroll
    for (int i = 0; i < CHUNK / 256; i++) {
        const long long e = e0 + t + i * 256;
        if (e < N_EDGES) atomicAdd(&hcnt[((unsigned)dst[e]) >> BUCK_SHIFT], 1u);
    }
    __syncthreads();
    for (int i = t; i < NBUCK; i += 256) {
        const unsigned c = hcnt[i];
        const unsigned r = c ? atomicAdd(&cntg[i], c) : 0u;
        hcur[i] = (unsigned)i * CAP + r;
    }
    __syncthreads();
#pragma unroll
    for (int i = 0; i < CHUNK / 256; i++) {
        const long long e = e0 + t + i * 256;
        if (e < N_EDGES) {
            const unsigned d = (unsigned)dst[e];
            const unsigned b = d >> BUCK_SHIFT;
            const unsigned pos = atomicAdd(&hcur[b], 1u);
            if (pos - b * CAP < CAP)
                bbuf[pos] = (unsigned)src[e] | ((d & (NODES_PER_BUCK - 1)) << 17);
        }
    }
}

// pass 2: per bucket (256 nodes), compute own gbase, build node-grouped CSR
// in LDS, flush coalesced; emit deg/rowstart/dinv.
__global__ __launch_bounds__(256) void p2_build(
        const unsigned* __restrict__ cntg,
        const unsigned* __restrict__ bbuf, int* __restrict__ csr,
        unsigned* __restrict__ deg, unsigned* __restrict__ rowstart,
        float* __restrict__ dinv) {
    __shared__ unsigned hist[NODES_PER_BUCK];
    __shared__ unsigned start[NODES_PER_BUCK];
    __shared__ unsigned cur[NODES_PER_BUCK];
    __shared__ unsigned s[256];
    __shared__ int lcsr[CAP];
    const int b = blockIdx.x;
    const int t = threadIdx.x;

    // gbase = sum_{i<b} min(cntg[i],CAP)   (b < 391 -> up to 2 entries/thread)
    unsigned pc = 0;
    if (t < b)       { unsigned c = cntg[t];       pc  = (c > CAP) ? CAP : c; }
    if (t + 256 < b) { unsigned c = cntg[t + 256]; pc += (c > CAP) ? CAP : c; }
    s[t] = pc;
    __syncthreads();
    for (int off = 128; off > 0; off >>= 1) {
        if (t < off) s[t] += s[t + off];
        __syncthreads();
    }
    const unsigned gbase = s[0];
    unsigned cnt = cntg[b]; if (cnt > CAP) cnt = CAP;
    const unsigned* mybuf = bbuf + (size_t)b * CAP;
    __syncthreads();

    hist[t] = 0;
    __syncthreads();
    for (unsigned i = t; i < cnt; i += 256) atomicAdd(&hist[mybuf[i] >> 17], 1u);
    __syncthreads();
    const unsigned v0 = hist[t];
    s[t] = v0;
    __syncthreads();
    for (int off = 1; off < 256; off <<= 1) {
        unsigned x = (t >= off) ? s[t - off] : 0u;
        __syncthreads();
        s[t] += x;
        __syncthreads();
    }
    const unsigned ex = s[t] - v0;
    start[t] = ex; cur[t] = ex;
    __syncthreads();
    for (unsigned i = t; i < cnt; i += 256) {
        const unsigned p = mybuf[i];
        const unsigned pos = atomicAdd(&cur[p >> 17], 1u);
        lcsr[pos] = (int)(p & 0x1FFFFu);
    }
    __syncthreads();
    for (unsigned i = t; i < cnt; i += 256) csr[gbase + i] = lcsr[i];
    const int n = b * NODES_PER_BUCK + t;
    if (n < N_NODES) {
        const unsigned d = hist[t];
        deg[n] = d;
        rowstart[n] = gbase + start[t];
        dinv[n] = rsqrtf((float)d + 1.0f);
    }
}

__device__ __forceinline__ float4 fma4(float s, float4 w, float4 a) {
    a.x = fmaf(s, w.x, a.x);
    a.y = fmaf(s, w.y, a.y);
    a.z = fmaf(s, w.z, a.z);
    a.w = fmaf(s, w.w, a.w);
    return a;
}

// y1 = (x @ W1) * dinv.  128 nodes/block, 4x4 register tile per thread.
// block 0 also zeroes psum/pcnt (needed before g8pool).
__global__ __launch_bounds__(256) void gemm1_kernel(
        const float* __restrict__ x, const float* __restrict__ W1,
        const float* __restrict__ dinv, float* __restrict__ y1,
        float* __restrict__ psum) {
    __shared__ float4 w4[IN_CH * 8];   // [k][cg]  32 KB
    __shared__ float4 xs4[128 * 9];    // [r][kq], pitch 9  18 KB
    const int t = threadIdx.x;

    if (blockIdx.x == 0) {
        for (int i = t; i < N_GRAPHS * OUT_CH + N_GRAPHS; i += 256) psum[i] = 0.0f;
    }

    const float4* W1v = (const float4*)W1;
#pragma unroll
    for (int i = 0; i < 8; i++) w4[t + i * 256] = W1v[t + i * 256];

    const int node0 = blockIdx.x * 128;
    const int cg = t & 7;
    const int ng = t >> 3;
    const float4* xv = (const float4*)x;

    float4 acc0 = {0, 0, 0, 0}, acc1 = {0, 0, 0, 0},
           acc2 = {0, 0, 0, 0}, acc3 = {0, 0, 0, 0};

#pragma unroll 1
    for (int kt = 0; kt < 8; kt++) {
        __syncthreads();
#pragma unroll
        for (int i = 0; i < 4; i++) {
            const int idx = t + i * 256;
            const int r = idx >> 3, kq = idx & 7;
            int gr = node0 + r; if (gr >= N_NODES) gr = N_NODES - 1;
            xs4[r * 9 + kq] = xv[(size_t)gr * 64 + kt * 8 + kq];
        }
        __syncthreads();
#pragma unroll
        for (int kq = 0; kq < 8; kq++) {
            const float4 xa = xs4[(ng + 0) * 9 + kq];
            const float4 xb = xs4[(ng + 32) * 9 + kq];
            const float4 xc = xs4[(ng + 64) * 9 + kq];
            const float4 xd = xs4[(ng + 96) * 9 + kq];
            const int kb = (kt * 32 + kq * 4) * 8 + cg;
            const float4 w0 = w4[kb];
            const float4 w1 = w4[kb + 8];
            const float4 w2 = w4[kb + 16];
            const float4 w3 = w4[kb + 24];
            acc0 = fma4(xa.x, w0, acc0); acc0 = fma4(xa.y, w1, acc0);
            acc0 = fma4(xa.z, w2, acc0); acc0 = fma4(xa.w, w3, acc0);
            acc1 = fma4(xb.x, w0, acc1); acc1 = fma4(xb.y, w1, acc1);
            acc1 = fma4(xb.z, w2, acc1); acc1 = fma4(xb.w, w3, acc1);
            acc2 = fma4(xc.x, w0, acc2); acc2 = fma4(xc.y, w1, acc2);
            acc2 = fma4(xc.z, w2, acc2); acc2 = fma4(xc.w, w3, acc2);
            acc3 = fma4(xd.x, w0, acc3); acc3 = fma4(xd.y, w1, acc3);
            acc3 = fma4(xd.z, w2, acc3); acc3 = fma4(xd.w, w3, acc3);
        }
    }

    float4* y1v = (float4*)y1;
#pragma unroll
    for (int i = 0; i < 4; i++) {
        const int n = node0 + ng + i * 32;
        if (n < N_NODES) {
            const float dv = dinv[n];
            float4 a = (i == 0) ? acc0 : (i == 1) ? acc1 : (i == 2) ? acc2 : acc3;
            a.x *= dv; a.y *= dv; a.z *= dv; a.w *= dv;
            y1v[(size_t)n * 8 + cg] = a;
        }
    }
}

// fused gather+layer2: 8 lanes/node, float4 row segments (4 ch per lane).
// agg = y1[n] + sum y1[s]; h = relu(agg*dinv+b1); y2 = (h @ W2) * dinv.
// 32 nodes/block; grid = 3125 exact.
__global__ __launch_bounds__(256) void g32l2_kernel(
        const unsigned* __restrict__ rowstart, const unsigned* __restrict__ deg,
        const int* __restrict__ csr, const float* __restrict__ y,
        const float* __restrict__ dinv, const float* __restrict__ b1,
        const float* __restrict__ W2, float* __restrict__ y2) {
    __shared__ float w2s[HID_CH][9];   // padded
    __shared__ float b1s[HID_CH];
    __shared__ float4 hbuf4[32][9];    // padded pitch 9
    const int t = threadIdx.x;
    { const int k = t >> 3, c = t & 7; w2s[k][c] = W2[t]; }
    if (t < HID_CH) b1s[t] = b1[t];
    __syncthreads();

    const int nl = t >> 3;          // node within block
    const int lane = t & 7;         // float4 slot; later: out channel
    const int node = blockIdx.x * 32 + nl;
    const unsigned cnt = deg[node];
    const unsigned base = rowstart[node];
    const float4* yv = (const float4*)y;
    float4 acc = yv[(size_t)node * 8 + lane];   // self-loop
    unsigned j = 0;
    for (; j + 8 <= cnt; j += 8) {
        const int s0 = csr[base + j];
        const int s1 = csr[base + j + 1];
        const int s2 = csr[base + j + 2];
        const int s3 = csr[base + j + 3];
        const int s4 = csr[base + j + 4];
        const int s5 = csr[base + j + 5];
        const int s6 = csr[base + j + 6];
        const int s7 = csr[base + j + 7];
        const float4 a0 = yv[(size_t)s0 * 8 + lane];
        const float4 a1 = yv[(size_t)s1 * 8 + lane];
        const float4 a2 = yv[(size_t)s2 * 8 + lane];
        const float4 a3 = yv[(size_t)s3 * 8 + lane];
        const float4 a4 = yv[(size_t)s4 * 8 + lane];
        const float4 a5 = yv[(size_t)s5 * 8 + lane];
        const float4 a6 = yv[(size_t)s6 * 8 + lane];
        const float4 a7 = yv[(size_t)s7 * 8 + lane];
        acc.x += ((a0.x + a1.x) + (a2.x + a3.x)) + ((a4.x + a5.x) + (a6.x + a7.x));
        acc.y += ((a0.y + a1.y) + (a2.y + a3.y)) + ((a4.y + a5.y) + (a6.y + a7.y));
        acc.z += ((a0.z + a1.z) + (a2.z + a3.z)) + ((a4.z + a5.z) + (a6.z + a7.z));
        acc.w += ((a0.w + a1.w) + (a2.w + a3.w)) + ((a4.w + a5.w) + (a6.w + a7.w));
    }
    for (; j < cnt; j++) {
        const int s0 = csr[base + j];
        const float4 a0 = yv[(size_t)s0 * 8 + lane];
        acc.x += a0.x; acc.y += a0.y; acc.z += a0.z; acc.w += a0.w;
    }
    const float dv = dinv[node];
    float4 h;
    h.x = fmaxf(fmaf(acc.x, dv, b1s[4 * lane + 0]), 0.0f);
    h.y = fmaxf(fmaf(acc.y, dv, b1s[4 * lane + 1]), 0.0f);
    h.z = fmaxf(fmaf(acc.z, dv, b1s[4 * lane + 2]), 0.0f);
    h.w = fmaxf(fmaf(acc.w, dv, b1s[4 * lane + 3]), 0.0f);
    hbuf4[nl][lane] = h;
    __syncthreads();
    // layer2: lane = out channel c; read all 32 h's of this node (broadcast)
    const float* hp = (const float*)&hbuf4[nl][0];
    float p = 0.0f;
#pragma unroll
    for (int k = 0; k < HID_CH; k++) p = fmaf(hp[k], w2s[k][lane], p);
    y2[(size_t)node * OUT_CH + lane] = p * dv;
}

// fused gather+pool: 8 lanes/node; o = relu(agg2*dinv+b2);
// per-graph LDS accumulators, flush [gmin,gmax] only. grid = 3125.
__global__ __launch_bounds__(256) void g8pool_kernel(
        const unsigned* __restrict__ rowstart, const unsigned* __restrict__ deg,
        const int* __restrict__ csr, const float* __restrict__ y,
        const float* __restrict__ dinv, const float* __restrict__ b2,
        const int* __restrict__ batch,
        float* __restrict__ psum, float* __restrict__ pcnt) {
    __shared__ float ls[N_GRAPHS * OUT_CH];
    __shared__ float lc[N_GRAPHS];
    __shared__ float b2s[OUT_CH];
    __shared__ int grange[2];
    const int t = threadIdx.x;
    ls[t] = 0.0f; ls[t + 256] = 0.0f;
    if (t < N_GRAPHS) lc[t] = 0.0f;
    if (t < OUT_CH) b2s[t] = b2[t];
    if (t == 0) { grange[0] = N_GRAPHS; grange[1] = -1; }
    __syncthreads();

    const int node = blockIdx.x * 32 + (t >> 3);
    const int lane = t & 7;
    const int g = batch[node];
    const unsigned cnt = deg[node];
    const unsigned base = rowstart[node];
    float acc = y[(size_t)node * OUT_CH + lane];
    unsigned j = 0;
    for (; j + 8 <= cnt; j += 8) {
        const int s0 = csr[base + j];
        const int s1 = csr[base + j + 1];
        const int s2 = csr[base + j + 2];
        const int s3 = csr[base + j + 3];
        const int s4 = csr[base + j + 4];
        const int s5 = csr[base + j + 5];
        const int s6 = csr[base + j + 6];
        const int s7 = csr[base + j + 7];
        const float a0 = y[(size_t)s0 * OUT_CH + lane];
        const float a1 = y[(size_t)s1 * OUT_CH + lane];
        const float a2 = y[(size_t)s2 * OUT_CH + lane];
        const float a3 = y[(size_t)s3 * OUT_CH + lane];
        const float a4 = y[(size_t)s4 * OUT_CH + lane];
        const float a5 = y[(size_t)s5 * OUT_CH + lane];
        const float a6 = y[(size_t)s6 * OUT_CH + lane];
        const float a7 = y[(size_t)s7 * OUT_CH + lane];
        acc += ((a0 + a1) + (a2 + a3)) + ((a4 + a5) + (a6 + a7));
    }
    for (; j < cnt; j++) acc += y[(size_t)csr[base + j] * OUT_CH + lane];

    const float o = fmaxf(fmaf(acc, dinv[node], b2s[lane]), 0.0f);
    atomicAdd(&ls[g * OUT_CH + lane], o);
    if (lane == 0) {
        atomicAdd(&lc[g], 1.0f);
        atomicMin(&grange[0], g);
        atomicMax(&grange[1], g);
    }
    __syncthreads();
    const int g0 = grange[0], g1 = grange[1];
    const int nent = (g1 - g0 + 1) * OUT_CH;
    for (int i = t; i < nent; i += 256)
        atomicAdd(&psum[g0 * OUT_CH + i], ls[g0 * OUT_CH + i]);
    for (int i = t; i < g1 - g0 + 1; i += 256)
        atomicAdd(&pcnt[g0 + i], lc[g0 + i]);
}

__global__ void logsoftmax_kernel(const float* __restrict__ psum,
                                  const float* __restrict__ pcnt,
                                  float* __restrict__ out) {
    const int g = threadIdx.x;
    if (g >= N_GRAPHS) return;
    const float cnt = fmaxf(pcnt[g], 1.0f);
    float p[OUT_CH];
    float m = -INFINITY;
#pragma unroll
    for (int c = 0; c < OUT_CH; c++) {
        p[c] = psum[g * OUT_CH + c] / cnt;
        m = fmaxf(m, p[c]);
    }
    float s = 0.0f;
#pragma unroll
    for (int c = 0; c < OUT_CH; c++) s += expf(p[c] - m);
    const float lse = logf(s);
#pragma unroll
    for (int c = 0; c < OUT_CH; c++) out[g * OUT_CH + c] = p[c] - m - lse;
}

extern "C" void kernel_launch(void* const* d_in, const int* in_sizes, int n_in,
                              void* d_out, int out_size, void* d_ws, size_t ws_size,
                              hipStream_t stream) {
    const float* x    = (const float*)d_in[0];
    const int* eidx   = (const int*)d_in[1];
    const int* batch  = (const int*)d_in[2];
    const float* W1   = (const float*)d_in[3];
    const float* b1   = (const float*)d_in[4];
    const float* W2   = (const float*)d_in[5];
    const float* b2   = (const float*)d_in[6];
    float* out = (float*)d_out;

    const int* src = eidx;
    const int* dst = eidx + N_EDGES;

    char* wsb = (char*)d_ws;
    unsigned* deg   = (unsigned*)(wsb) + OFF_DEG;
    float*    dinv  = (float*)(wsb) + OFF_DINV;
    unsigned* rows  = (unsigned*)(wsb) + OFF_ROWS;
    unsigned* cntg  = (unsigned*)(wsb) + OFF_CNTG;
    int*      csr   = (int*)(wsb) + OFF_CSR;
    float*    y1    = (float*)(wsb) + OFF_Y1;
    unsigned* bbuf  = (unsigned*)(wsb) + OFF_BBUF;
    float*    y2    = (float*)(wsb) + OFF_Y2;
    float*    psum  = (float*)(wsb) + OFF_PSUM;
    float*    pcnt  = (float*)(wsb) + OFF_PCNT;

    zero_kernel<<<1, 256, 0, stream>>>(cntg);
    p1_partition<<<NBLK_P1, 256, 0, stream>>>(src, dst, cntg, bbuf);
    p2_build<<<NBUCK, 256, 0, stream>>>(cntg, bbuf, csr, deg, rows, dinv);
    gemm1_kernel<<<(N_NODES + 127) / 128, 256, 0, stream>>>(x, W1, dinv, y1, psum);
    g32l2_kernel<<<N_NODES / 32, 256, 0, stream>>>(rows, deg, csr, y1, dinv, b1, W2, y2);
    g8pool_kernel<<<N_NODES / 32, 256, 0, stream>>>(rows, deg, csr, y2, dinv, b2, batch, psum, pcnt);
    logsoftmax_kernel<<<1, 64, 0, stream>>>(psum, pcnt, out);
}

// Round 8
// 151.257 us; speedup vs baseline: 2.9411x; 1.1212x over previous
//
#include <hip/hip_runtime.h>
#include <hip/hip_bf16.h>
#include <math.h>

#define N_NODES 100000
#define N_EDGES 1600000
#define IN_CH 256
#define HID_CH 32
#define OUT_CH 8
#define N_GRAPHS 64

// bucket sort params (128 nodes / bucket)
#define BUCK_SHIFT 7
#define NODES_PER_BUCK 128
#define NBUCK ((N_NODES + NODES_PER_BUCK - 1) / NODES_PER_BUCK)   // 782
#define CAP 2560                      // mean 2048 + 11 sigma
#define CHUNK 2048
#define NBLK_P1 ((N_EDGES + CHUNK - 1) / CHUNK)                   // 782

#define DUMMY_ROW N_NODES             // zeroed row for gather-tail padding
#define Y_ROWS 100008                 // N_NODES + dummy + pad

// ---------------- workspace layout (in 4-byte words) ----------------
#define OFF_DEG    0                                // uint[N]
#define OFF_DINV   (OFF_DEG + N_NODES)              // float[N]
#define OFF_ROWS   (OFF_DINV + N_NODES)             // uint[N]
#define OFF_CNTG   (OFF_ROWS + N_NODES)             // uint[784] (pad->8B align)
#define OFF_CSR    (OFF_CNTG + 784)                 // int[E]
#define OFF_Y1     (OFF_CSR + N_EDGES)              // bf16[Y_ROWS*32] (uint2 rows x8)
#define OFF_BBUF   (OFF_Y1 + Y_ROWS*16)             // uint[NBUCK*CAP]
#define OFF_Y2     (OFF_BBUF + NBUCK*CAP)           // bf16[Y_ROWS*8]
#define OFF_PSUM   (OFF_Y2 + Y_ROWS*4)              // float[64*8]
#define OFF_PCNT   (OFF_PSUM + N_GRAPHS*OUT_CH)     // float[64]

// f32 -> bf16 (RNE) bit helpers
__device__ __forceinline__ unsigned bfr(float f) {
    unsigned u = __float_as_uint(f);
    return (u + 0x7fffu + ((u >> 16) & 1u)) >> 16;
}
__device__ __forceinline__ float bf_lo(unsigned w) { return __uint_as_float(w << 16); }
__device__ __forceinline__ float bf_hi(unsigned w) { return __uint_as_float(w & 0xffff0000u); }

__global__ void zero_kernel(unsigned* __restrict__ cntg, uint2* __restrict__ y1v2,
                            unsigned short* __restrict__ y2bf) {
    const int t = threadIdx.x;
    for (int i = t; i < NBUCK; i += 256) cntg[i] = 0u;
    if (t < 8) y1v2[(size_t)DUMMY_ROW * 8 + t] = make_uint2(0u, 0u);
    if (t < 8) y2bf[(size_t)DUMMY_ROW * 8 + t] = 0;
}

// pass 1: partition edges into per-bucket arenas, packed (src | dlow<<17)
// edges staged in registers (8 per thread), single global read of src/dst
__global__ __launch_bounds__(256) void p1_partition(
        const int* __restrict__ src, const int* __restrict__ dst,
        unsigned* __restrict__ cntg, unsigned* __restrict__ bbuf) {
    __shared__ unsigned hcnt[NBUCK];
    __shared__ unsigned hcur[NBUCK];
    const int t = threadIdx.x;
    const long long e0 = (long long)blockIdx.x * CHUNK;

    int rs[8]; unsigned rd[8];
#pragma unroll
    for (int i = 0; i < 8; i++) {
        const long long e = e0 + t + i * 256;
        const bool v = (e < N_EDGES);
        rs[i] = v ? src[e] : 0;
        rd[i] = v ? (unsigned)dst[e] : 0xFFFFFFFFu;
    }
    for (int i = t; i < NBUCK; i += 256) hcnt[i] = 0;
    __syncthreads();
#pragma unroll
    for (int i = 0; i < 8; i++)
        if (rd[i] != 0xFFFFFFFFu) atomicAdd(&hcnt[rd[i] >> BUCK_SHIFT], 1u);
    __syncthreads();
    for (int i = t; i < NBUCK; i += 256) {
        const unsigned c = hcnt[i];
        const unsigned r = c ? atomicAdd(&cntg[i], c) : 0u;
        hcur[i] = (unsigned)i * CAP + r;
    }
    __syncthreads();
#pragma unroll
    for (int i = 0; i < 8; i++) {
        if (rd[i] != 0xFFFFFFFFu) {
            const unsigned b = rd[i] >> BUCK_SHIFT;
            const unsigned pos = atomicAdd(&hcur[b], 1u);
            if (pos - b * CAP < CAP)
                bbuf[pos] = (unsigned)rs[i] | ((rd[i] & (NODES_PER_BUCK - 1)) << 17);
        }
    }
}

// pass 2: per bucket (128 nodes), compute own gbase, build node-grouped CSR
// in LDS, flush coalesced; emit deg/rowstart/dinv.
__global__ __launch_bounds__(256) void p2_build(
        const unsigned* __restrict__ cntg,
        const unsigned* __restrict__ bbuf, int* __restrict__ csr,
        unsigned* __restrict__ deg, unsigned* __restrict__ rowstart,
        float* __restrict__ dinv) {
    __shared__ unsigned hist[NODES_PER_BUCK];
    __shared__ unsigned start[NODES_PER_BUCK];
    __shared__ unsigned cur[NODES_PER_BUCK];
    __shared__ unsigned s[256];
    __shared__ int lcsr[CAP];
    const int b = blockIdx.x;
    const int t = threadIdx.x;

    // gbase = sum_{i<b} min(cntg[i],CAP)
    unsigned pc = 0;
    for (int i = t; i < b; i += 256) {
        unsigned c = cntg[i]; pc += (c > CAP) ? CAP : c;
    }
    s[t] = pc;
    __syncthreads();
    for (int off = 128; off > 0; off >>= 1) {
        if (t < off) s[t] += s[t + off];
        __syncthreads();
    }
    const unsigned gbase = s[0];
    unsigned cnt = cntg[b]; if (cnt > CAP) cnt = CAP;
    const unsigned* mybuf = bbuf + (size_t)b * CAP;
    __syncthreads();

    if (t < NODES_PER_BUCK) hist[t] = 0;
    __syncthreads();
    for (unsigned i = t; i < cnt; i += 256) atomicAdd(&hist[mybuf[i] >> 17], 1u);
    __syncthreads();
    const unsigned v0 = (t < NODES_PER_BUCK) ? hist[t] : 0u;
    s[t] = v0;
    __syncthreads();
    for (int off = 1; off < 256; off <<= 1) {
        unsigned x = (t >= off) ? s[t - off] : 0u;
        __syncthreads();
        s[t] += x;
        __syncthreads();
    }
    if (t < NODES_PER_BUCK) {
        const unsigned ex = s[t] - v0;
        start[t] = ex; cur[t] = ex;
    }
    __syncthreads();
    for (unsigned i = t; i < cnt; i += 256) {
        const unsigned p = mybuf[i];
        const unsigned pos = atomicAdd(&cur[p >> 17], 1u);
        lcsr[pos] = (int)(p & 0x1FFFFu);
    }
    __syncthreads();
    for (unsigned i = t; i < cnt; i += 256) csr[gbase + i] = lcsr[i];
    const int n = b * NODES_PER_BUCK + t;
    if (t < NODES_PER_BUCK && n < N_NODES) {
        const unsigned d = hist[t];
        deg[n] = d;
        rowstart[n] = gbase + start[t];
        dinv[n] = rsqrtf((float)d + 1.0f);
    }
}

__device__ __forceinline__ float4 fma4(float s, float4 w, float4 a) {
    a.x = fmaf(s, w.x, a.x);
    a.y = fmaf(s, w.y, a.y);
    a.z = fmaf(s, w.z, a.z);
    a.w = fmaf(s, w.w, a.w);
    return a;
}

// y1 = bf16((x @ W1) * dinv).  128 nodes/block, 4x4 register tile per thread.
// block 0 also zeroes psum/pcnt (needed before g8pool).
__global__ __launch_bounds__(256) void gemm1_kernel(
        const float* __restrict__ x, const float* __restrict__ W1,
        const float* __restrict__ dinv, uint2* __restrict__ y1v2,
        float* __restrict__ psum) {
    __shared__ float4 w4[IN_CH * 8];   // [k][cg]  32 KB
    __shared__ float4 xs4[128 * 9];    // [r][kq], pitch 9  18 KB
    const int t = threadIdx.x;

    if (blockIdx.x == 0) {
        for (int i = t; i < N_GRAPHS * OUT_CH + N_GRAPHS; i += 256) psum[i] = 0.0f;
    }

    const float4* W1v = (const float4*)W1;
#pragma unroll
    for (int i = 0; i < 8; i++) w4[t + i * 256] = W1v[t + i * 256];

    const int node0 = blockIdx.x * 128;
    const int cg = t & 7;
    const int ng = t >> 3;
    const float4* xv = (const float4*)x;

    float4 acc0 = {0, 0, 0, 0}, acc1 = {0, 0, 0, 0},
           acc2 = {0, 0, 0, 0}, acc3 = {0, 0, 0, 0};

#pragma unroll 1
    for (int kt = 0; kt < 8; kt++) {
        __syncthreads();
#pragma unroll
        for (int i = 0; i < 4; i++) {
            const int idx = t + i * 256;
            const int r = idx >> 3, kq = idx & 7;
            int gr = node0 + r; if (gr >= N_NODES) gr = N_NODES - 1;
            xs4[r * 9 + kq] = xv[(size_t)gr * 64 + kt * 8 + kq];
        }
        __syncthreads();
#pragma unroll
        for (int kq = 0; kq < 8; kq++) {
            const float4 xa = xs4[(ng + 0) * 9 + kq];
            const float4 xb = xs4[(ng + 32) * 9 + kq];
            const float4 xc = xs4[(ng + 64) * 9 + kq];
            const float4 xd = xs4[(ng + 96) * 9 + kq];
            const int kb = (kt * 32 + kq * 4) * 8 + cg;
            const float4 w0 = w4[kb];
            const float4 w1 = w4[kb + 8];
            const float4 w2 = w4[kb + 16];
            const float4 w3 = w4[kb + 24];
            acc0 = fma4(xa.x, w0, acc0); acc0 = fma4(xa.y, w1, acc0);
            acc0 = fma4(xa.z, w2, acc0); acc0 = fma4(xa.w, w3, acc0);
            acc1 = fma4(xb.x, w0, acc1); acc1 = fma4(xb.y, w1, acc1);
            acc1 = fma4(xb.z, w2, acc1); acc1 = fma4(xb.w, w3, acc1);
            acc2 = fma4(xc.x, w0, acc2); acc2 = fma4(xc.y, w1, acc2);
            acc2 = fma4(xc.z, w2, acc2); acc2 = fma4(xc.w, w3, acc2);
            acc3 = fma4(xd.x, w0, acc3); acc3 = fma4(xd.y, w1, acc3);
            acc3 = fma4(xd.z, w2, acc3); acc3 = fma4(xd.w, w3, acc3);
        }
    }

#pragma unroll
    for (int i = 0; i < 4; i++) {
        const int n = node0 + ng + i * 32;
        if (n < N_NODES) {
            const float dv = dinv[n];
            float4 a = (i == 0) ? acc0 : (i == 1) ? acc1 : (i == 2) ? acc2 : acc3;
            uint2 pk;
            pk.x = bfr(a.x * dv) | (bfr(a.y * dv) << 16);
            pk.y = bfr(a.z * dv) | (bfr(a.w * dv) << 16);
            y1v2[(size_t)n * 8 + cg] = pk;
        }
    }
}

// fused gather+layer2: 8 lanes/node, bf16x4 (uint2) row segments.
// agg = y1[n] + sum y1[s]; h = relu(agg*dinv+b1); y2 = bf16((h @ W2)*dinv).
// tail edges padded with DUMMY_ROW (zeros) -> full memory-level parallelism.
__global__ __launch_bounds__(256) void g32l2_kernel(
        const unsigned* __restrict__ rowstart, const unsigned* __restrict__ deg,
        const int* __restrict__ csr, const uint2* __restrict__ y1v2,
        const float* __restrict__ dinv, const float* __restrict__ b1,
        const float* __restrict__ W2, unsigned short* __restrict__ y2bf) {
    __shared__ float w2s[HID_CH][9];
    __shared__ float b1s[HID_CH];
    __shared__ float4 hbuf4[32][9];
    const int t = threadIdx.x;
    { const int k = t >> 3, c = t & 7; w2s[k][c] = W2[t]; }
    if (t < HID_CH) b1s[t] = b1[t];
    __syncthreads();

    const int nl = t >> 3;
    const int lane = t & 7;
    const int node = blockIdx.x * 32 + nl;
    const unsigned cnt = deg[node];
    const unsigned base = rowstart[node];

    uint2 sv = y1v2[(size_t)node * 8 + lane];   // self-loop
    float ax = bf_lo(sv.x), ay = bf_hi(sv.x), az = bf_lo(sv.y), aw = bf_hi(sv.y);

    for (unsigned j = 0; j < cnt; j += 8) {
        int si[8];
#pragma unroll
        for (int i = 0; i < 8; i++) {
            si[i] = DUMMY_ROW;
            if (j + i < cnt) si[i] = csr[base + j + i];
        }
        uint2 a0 = y1v2[(size_t)si[0] * 8 + lane];
        uint2 a1 = y1v2[(size_t)si[1] * 8 + lane];
        uint2 a2 = y1v2[(size_t)si[2] * 8 + lane];
        uint2 a3 = y1v2[(size_t)si[3] * 8 + lane];
        uint2 a4 = y1v2[(size_t)si[4] * 8 + lane];
        uint2 a5 = y1v2[(size_t)si[5] * 8 + lane];
        uint2 a6 = y1v2[(size_t)si[6] * 8 + lane];
        uint2 a7 = y1v2[(size_t)si[7] * 8 + lane];
        ax += ((bf_lo(a0.x) + bf_lo(a1.x)) + (bf_lo(a2.x) + bf_lo(a3.x)))
            + ((bf_lo(a4.x) + bf_lo(a5.x)) + (bf_lo(a6.x) + bf_lo(a7.x)));
        ay += ((bf_hi(a0.x) + bf_hi(a1.x)) + (bf_hi(a2.x) + bf_hi(a3.x)))
            + ((bf_hi(a4.x) + bf_hi(a5.x)) + (bf_hi(a6.x) + bf_hi(a7.x)));
        az += ((bf_lo(a0.y) + bf_lo(a1.y)) + (bf_lo(a2.y) + bf_lo(a3.y)))
            + ((bf_lo(a4.y) + bf_lo(a5.y)) + (bf_lo(a6.y) + bf_lo(a7.y)));
        aw += ((bf_hi(a0.y) + bf_hi(a1.y)) + (bf_hi(a2.y) + bf_hi(a3.y)))
            + ((bf_hi(a4.y) + bf_hi(a5.y)) + (bf_hi(a6.y) + bf_hi(a7.y)));
    }
    const float dv = dinv[node];
    float4 h;
    h.x = fmaxf(fmaf(ax, dv, b1s[4 * lane + 0]), 0.0f);
    h.y = fmaxf(fmaf(ay, dv, b1s[4 * lane + 1]), 0.0f);
    h.z = fmaxf(fmaf(az, dv, b1s[4 * lane + 2]), 0.0f);
    h.w = fmaxf(fmaf(aw, dv, b1s[4 * lane + 3]), 0.0f);
    hbuf4[nl][lane] = h;
    __syncthreads();
    const float* hp = (const float*)&hbuf4[nl][0];
    float p = 0.0f;
#pragma unroll
    for (int k = 0; k < HID_CH; k++) p = fmaf(hp[k], w2s[k][lane], p);
    y2bf[(size_t)node * 8 + lane] = (unsigned short)bfr(p * dv);
}

// fused gather+pool: 8 lanes/node, bf16 scalar loads; tail padded with dummy.
__global__ __launch_bounds__(256) void g8pool_kernel(
        const unsigned* __restrict__ rowstart, const unsigned* __restrict__ deg,
        const int* __restrict__ csr, const unsigned short* __restrict__ y2bf,
        const float* __restrict__ dinv, const float* __restrict__ b2,
        const int* __restrict__ batch,
        float* __restrict__ psum, float* __restrict__ pcnt) {
    __shared__ float ls[N_GRAPHS * OUT_CH];
    __shared__ float lc[N_GRAPHS];
    __shared__ float b2s[OUT_CH];
    __shared__ int grange[2];
    const int t = threadIdx.x;
    ls[t] = 0.0f; ls[t + 256] = 0.0f;
    if (t < N_GRAPHS) lc[t] = 0.0f;
    if (t < OUT_CH) b2s[t] = b2[t];
    if (t == 0) { grange[0] = N_GRAPHS; grange[1] = -1; }
    __syncthreads();

    const int node = blockIdx.x * 32 + (t >> 3);
    const int lane = t & 7;
    const int g = batch[node];
    const unsigned cnt = deg[node];
    const unsigned base = rowstart[node];
    float acc = __uint_as_float((unsigned)y2bf[(size_t)node * 8 + lane] << 16);

    for (unsigned j = 0; j < cnt; j += 8) {
        int si[8];
#pragma unroll
        for (int i = 0; i < 8; i++) {
            si[i] = DUMMY_ROW;
            if (j + i < cnt) si[i] = csr[base + j + i];
        }
        const float a0 = __uint_as_float((unsigned)y2bf[(size_t)si[0] * 8 + lane] << 16);
        const float a1 = __uint_as_float((unsigned)y2bf[(size_t)si[1] * 8 + lane] << 16);
        const float a2 = __uint_as_float((unsigned)y2bf[(size_t)si[2] * 8 + lane] << 16);
        const float a3 = __uint_as_float((unsigned)y2bf[(size_t)si[3] * 8 + lane] << 16);
        const float a4 = __uint_as_float((unsigned)y2bf[(size_t)si[4] * 8 + lane] << 16);
        const float a5 = __uint_as_float((unsigned)y2bf[(size_t)si[5] * 8 + lane] << 16);
        const float a6 = __uint_as_float((unsigned)y2bf[(size_t)si[6] * 8 + lane] << 16);
        const float a7 = __uint_as_float((unsigned)y2bf[(size_t)si[7] * 8 + lane] << 16);
        acc += ((a0 + a1) + (a2 + a3)) + ((a4 + a5) + (a6 + a7));
    }

    const float o = fmaxf(fmaf(acc, dinv[node], b2s[lane]), 0.0f);
    atomicAdd(&ls[g * OUT_CH + lane], o);
    if (lane == 0) {
        atomicAdd(&lc[g], 1.0f);
        atomicMin(&grange[0], g);
        atomicMax(&grange[1], g);
    }
    __syncthreads();
    const int g0 = grange[0], g1 = grange[1];
    const int nent = (g1 - g0 + 1) * OUT_CH;
    for (int i = t; i < nent; i += 256)
        atomicAdd(&psum[g0 * OUT_CH + i], ls[g0 * OUT_CH + i]);
    for (int i = t; i < g1 - g0 + 1; i += 256)
        atomicAdd(&pcnt[g0 + i], lc[g0 + i]);
}

__global__ void logsoftmax_kernel(const float* __restrict__ psum,
                                  const float* __restrict__ pcnt,
                                  float* __restrict__ out) {
    const int g = threadIdx.x;
    if (g >= N_GRAPHS) return;
    const float cnt = fmaxf(pcnt[g], 1.0f);
    float p[OUT_CH];
    float m = -INFINITY;
#pragma unroll
    for (int c = 0; c < OUT_CH; c++) {
        p[c] = psum[g * OUT_CH + c] / cnt;
        m = fmaxf(m, p[c]);
    }
    float s = 0.0f;
#pragma unroll
    for (int c = 0; c < OUT_CH; c++) s += expf(p[c] - m);
    const float lse = logf(s);
#pragma unroll
    for (int c = 0; c < OUT_CH; c++) out[g * OUT_CH + c] = p[c] - m - lse;
}

extern "C" void kernel_launch(void* const* d_in, const int* in_sizes, int n_in,
                              void* d_out, int out_size, void* d_ws, size_t ws_size,
                              hipStream_t stream) {
    const float* x    = (const float*)d_in[0];
    const int* eidx   = (const int*)d_in[1];
    const int* batch  = (const int*)d_in[2];
    const float* W1   = (const float*)d_in[3];
    const float* b1   = (const float*)d_in[4];
    const float* W2   = (const float*)d_in[5];
    const float* b2   = (const float*)d_in[6];
    float* out = (float*)d_out;

    const int* src = eidx;
    const int* dst = eidx + N_EDGES;

    char* wsb = (char*)d_ws;
    unsigned*       deg   = (unsigned*)(wsb) + OFF_DEG;
    float*          dinv  = (float*)(wsb) + OFF_DINV;
    unsigned*       rows  = (unsigned*)(wsb) + OFF_ROWS;
    unsigned*       cntg  = (unsigned*)(wsb) + OFF_CNTG;
    int*            csr   = (int*)(wsb) + OFF_CSR;
    uint2*          y1v2  = (uint2*)((unsigned*)(wsb) + OFF_Y1);
    unsigned*       bbuf  = (unsigned*)(wsb) + OFF_BBUF;
    unsigned short* y2bf  = (unsigned short*)((unsigned*)(wsb) + OFF_Y2);
    float*          psum  = (float*)(wsb) + OFF_PSUM;
    float*          pcnt  = (float*)(wsb) + OFF_PCNT;

    zero_kernel<<<1, 256, 0, stream>>>(cntg, y1v2, y2bf);
    p1_partition<<<NBLK_P1, 256, 0, stream>>>(src, dst, cntg, bbuf);
    p2_build<<<NBUCK, 256, 0, stream>>>(cntg, bbuf, csr, deg, rows, dinv);
    gemm1_kernel<<<(N_NODES + 127) / 128, 256, 0, stream>>>(x, W1, dinv, y1v2, psum);
    g32l2_kernel<<<N_NODES / 32, 256, 0, stream>>>(rows, deg, csr, y1v2, dinv, b1, W2, y2bf);
    g8pool_kernel<<<N_NODES / 32, 256, 0, stream>>>(rows, deg, csr, y2bf, dinv, b2, batch, psum, pcnt);
    logsoftmax_kernel<<<1, 64, 0, stream>>>(psum, pcnt, out);
}